// Round 1
// baseline (3780.262 us; speedup 1.0000x reference)
//
#include <hip/hip_runtime.h>
#include <hip/hip_bf16.h>
#include <cstdint>

#define B_SZ 2
#define DIM 256
#define L_SEQ 4096
#define D_INNER 512
#define DT_RANK 16
#define D_STATE 16

__device__ __forceinline__ float silu_f(float v) {
    return v / (1.0f + __expf(-v));
}
__device__ __forceinline__ float softplus_f(float v) {
    return (v > 20.0f) ? v : log1pf(__expf(v));
}
// direction map: sequence position p -> original flat index l
__device__ __forceinline__ int dir_map(int p, int dirmode) {
    if (dirmode == 0) return p;
    if (dirmode == 1) return (L_SEQ - 1) - p;
    return ((p & 63) << 6) | (p >> 6);   // 64x64 transpose
}

// ---------------------------------------------------------------------------
// Kernel 1: LayerNorm over channels + in_proj GEMM (8192 x 1024, K=256).
// Block handles 4 rows (b, l0..l0+3). Wave w does LN of row w; proj phase:
// thread t computes outputs j = t + 256*jj for all 4 rows.
// Writes xin[b,l,0..511] and sz[b,l,0..511] = silu(z).
// ---------------------------------------------------------------------------
__global__ __launch_bounds__(256) void k_ln_inproj(
    const float* __restrict__ x, const float* __restrict__ lnw,
    const float* __restrict__ lnb, const float* __restrict__ W,
    float* __restrict__ xin, float* __restrict__ sz)
{
    __shared__ float xn[4][DIM];
    const int b  = blockIdx.x >> 10;            // 1024 blocks per batch
    const int l0 = (blockIdx.x & 1023) << 2;
    const int t  = threadIdx.x;
    const int wave = t >> 6, lane = t & 63;

    const float* xb = x + (size_t)b * DIM * L_SEQ;
    const int l = l0 + wave;
    float v[4];
    float sum = 0.f, sq = 0.f;
#pragma unroll
    for (int k = 0; k < 4; ++k) {
        const int c = lane + 64 * k;
        v[k] = xb[(size_t)c * L_SEQ + l];
        sum += v[k];
        sq  += v[k] * v[k];
    }
#pragma unroll
    for (int m = 32; m >= 1; m >>= 1) {
        sum += __shfl_xor(sum, m);
        sq  += __shfl_xor(sq, m);
    }
    const float mu   = sum * (1.0f / DIM);
    const float var  = sq * (1.0f / DIM) - mu * mu;
    const float rstd = rsqrtf(var + 1e-5f);
#pragma unroll
    for (int k = 0; k < 4; ++k) {
        const int c = lane + 64 * k;
        xn[wave][c] = (v[k] - mu) * rstd * lnw[c] + lnb[c];
    }
    __syncthreads();

    float acc[4][4];
#pragma unroll
    for (int jj = 0; jj < 4; ++jj)
#pragma unroll
        for (int r = 0; r < 4; ++r) acc[jj][r] = 0.f;

    for (int c = 0; c < DIM; c += 4) {
        float4 xv[4];
#pragma unroll
        for (int r = 0; r < 4; ++r) xv[r] = *(const float4*)&xn[r][c];
#pragma unroll
        for (int jj = 0; jj < 4; ++jj) {
            const int j = t + 256 * jj;
            const float4 wv = *(const float4*)&W[(size_t)j * DIM + c];
#pragma unroll
            for (int r = 0; r < 4; ++r) {
                acc[jj][r] = fmaf(wv.x, xv[r].x,
                             fmaf(wv.y, xv[r].y,
                             fmaf(wv.z, xv[r].z,
                             fmaf(wv.w, xv[r].w, acc[jj][r]))));
            }
        }
    }
#pragma unroll
    for (int jj = 0; jj < 4; ++jj) {
        const int j = t + 256 * jj;
#pragma unroll
        for (int r = 0; r < 4; ++r) {
            const size_t row = (size_t)b * L_SEQ + (l0 + r);
            if (j < D_INNER) xin[row * D_INNER + j] = acc[jj][r];
            else             sz[row * D_INNER + (j - D_INNER)] = silu_f(acc[jj][r]);
        }
    }
}

// ---------------------------------------------------------------------------
// Kernel 2: causal depthwise conv (K=4) + SiLU into sequence order for a
// given direction. Block = 256 threads = half of one p-row's channels.
// ---------------------------------------------------------------------------
__global__ __launch_bounds__(256) void k_conv(
    const float* __restrict__ xin, const float* __restrict__ cw,
    const float* __restrict__ cb, float* __restrict__ xc, int dirmode)
{
    const int gid = blockIdx.x;              // B * L * 2
    const int b   = gid >> 13;
    const int rem = gid & 8191;
    const int p   = rem >> 1;
    const int d   = ((rem & 1) << 8) + threadIdx.x;

    float acc = cb[d];
#pragma unroll
    for (int k = 0; k < 4; ++k) {
        const int pk = p - 3 + k;
        if (pk < 0) continue;
        const int lo = dir_map(pk, dirmode);
        acc = fmaf(xin[((size_t)b * L_SEQ + lo) * D_INNER + d], cw[d * 4 + k], acc);
    }
    xc[((size_t)b * L_SEQ + p) * D_INNER + d] = silu_f(acc);
}

// ---------------------------------------------------------------------------
// Kernel 3: x_proj (48 outputs, K=512) + dt_proj (512 outputs, K=16) +
// softplus. One block per (b,p) row; xc row staged in LDS.
// Writes dt[b,p,0..511] and bc[b,p,0..31] (B then C).
// ---------------------------------------------------------------------------
__global__ __launch_bounds__(256) void k_proj(
    const float* __restrict__ xc, const float* __restrict__ xpw,
    const float* __restrict__ dtw, const float* __restrict__ dtb,
    float* __restrict__ dt, float* __restrict__ bc)
{
    const int b = blockIdx.x >> 12;
    const int p = blockIdx.x & 4095;
    __shared__ float xrow[D_INNER];
    __shared__ float xdbl[48];
    const int t = threadIdx.x;
    const float* src = xc + ((size_t)b * L_SEQ + p) * D_INNER;
    xrow[t]       = src[t];
    xrow[t + 256] = src[t + 256];
    __syncthreads();

    if (t < 48) {
        float a = 0.f;
        for (int c = 0; c < D_INNER; c += 4) {
            const float4 wv = *(const float4*)&xpw[(size_t)t * D_INNER + c];
            a = fmaf(wv.x, xrow[c],
                fmaf(wv.y, xrow[c + 1],
                fmaf(wv.z, xrow[c + 2],
                fmaf(wv.w, xrow[c + 3], a))));
        }
        xdbl[t] = a;
    }
    __syncthreads();

#pragma unroll
    for (int jj = 0; jj < 2; ++jj) {
        const int dd = t + jj * 256;
        float a = dtb[dd];
#pragma unroll
        for (int r = 0; r < DT_RANK; r += 4) {
            const float4 wv = *(const float4*)&dtw[dd * DT_RANK + r];
            a = fmaf(wv.x, xdbl[r],
                fmaf(wv.y, xdbl[r + 1],
                fmaf(wv.z, xdbl[r + 2],
                fmaf(wv.w, xdbl[r + 3], a))));
        }
        dt[((size_t)b * L_SEQ + p) * D_INNER + dd] = softplus_f(a);
    }
    if (t < 32)
        bc[((size_t)b * L_SEQ + p) * 32 + t] = xdbl[16 + t];
}

// ---------------------------------------------------------------------------
// Kernel 4: selective scan. Block = (b, group of 16 channels); thread =
// (d_local, s). Chunks of 128 steps staged in LDS; h kept in registers.
// Epilogue applies + xc*D, * silu(z) at the mapped original index, and
// stores/accumulates into yacc.
// ---------------------------------------------------------------------------
__global__ __launch_bounds__(256) void k_scan(
    const float* __restrict__ dt, const float* __restrict__ xc,
    const float* __restrict__ bcbuf, const float* __restrict__ A_log,
    const float* __restrict__ Dp, const float* __restrict__ sz,
    float* __restrict__ yacc, int dirmode, int accum)
{
    const int b    = blockIdx.x >> 5;
    const int dblk = blockIdx.x & 31;
    const int t    = threadIdx.x;
    const int dl   = t >> 4;
    const int s    = t & 15;
    const int d    = dblk * 16 + dl;

    const float As = -__expf(A_log[d * D_STATE + s]);
    const float Dv = Dp[d];
    float h = 0.f;

    __shared__ float dtc[128 * 16];
    __shared__ float xcc[128 * 16];
    __shared__ float bcc[128 * 32];
    __shared__ float ybuf[128 * 16];

    const size_t rowbase = (size_t)b * L_SEQ;

    for (int chunk = 0; chunk < 32; ++chunk) {
        const int p0 = chunk * 128;
        // stage dt and xc chunks: 2048 floats each = 512 float4
#pragma unroll
        for (int rep = 0; rep < 2; ++rep) {
            const int idx = rep * 256 + t;
            const int j = idx >> 2, c4 = (idx & 3) << 2;
            const size_t go = (rowbase + p0 + j) * D_INNER + dblk * 16 + c4;
            *(float4*)&dtc[j * 16 + c4] = *(const float4*)(dt + go);
            *(float4*)&xcc[j * 16 + c4] = *(const float4*)(xc + go);
        }
        // stage BC chunk: 4096 floats = 1024 float4
#pragma unroll
        for (int rep = 0; rep < 4; ++rep) {
            const int idx = rep * 256 + t;
            const int j = idx >> 3, c4 = (idx & 7) << 2;
            *(float4*)&bcc[j * 32 + c4] =
                *(const float4*)(bcbuf + (rowbase + p0 + j) * 32 + c4);
        }
        __syncthreads();

#pragma unroll 4
        for (int j = 0; j < 128; ++j) {
            const float dtv = dtc[j * 16 + dl];
            const float xv  = xcc[j * 16 + dl];
            const float Bv  = bcc[j * 32 + s];
            const float Cv  = bcc[j * 32 + 16 + s];
            const float dA  = __expf(dtv * As);
            h = fmaf(dA, h, dtv * xv * Bv);
            float yc = h * Cv;
            yc += __shfl_xor(yc, 1);
            yc += __shfl_xor(yc, 2);
            yc += __shfl_xor(yc, 4);
            yc += __shfl_xor(yc, 8);
            if (s == 0) ybuf[j * 16 + dl] = yc + xv * Dv;
        }
        __syncthreads();

        // write back through the direction map, * silu(z)
#pragma unroll
        for (int rep = 0; rep < 8; ++rep) {
            const int e = rep * 256 + t;
            const int j = e >> 4, dl2 = e & 15;
            const int lo = dir_map(p0 + j, dirmode);
            const size_t o = (rowbase + lo) * D_INNER + dblk * 16 + dl2;
            const float val = ybuf[j * 16 + dl2] * sz[o];
            if (accum) yacc[o] += val;
            else       yacc[o] = val;
        }
        __syncthreads();
    }
}

// ---------------------------------------------------------------------------
// Kernel 5: out_proj (256 outputs, K=512) + residual. Block = 4 rows.
// ---------------------------------------------------------------------------
__global__ __launch_bounds__(256) void k_out(
    const float* __restrict__ yacc, const float* __restrict__ W,
    const float* __restrict__ x, float* __restrict__ out)
{
    __shared__ float yr[4][D_INNER];
    const int b  = blockIdx.x >> 10;
    const int l0 = (blockIdx.x & 1023) << 2;
    const int t  = threadIdx.x;
#pragma unroll
    for (int rep = 0; rep < 2; ++rep) {
        const int idx = rep * 256 + t;          // 512 float4
        const int r = idx >> 7, c = (idx & 127) << 2;
        *(float4*)&yr[r][c] =
            *(const float4*)(yacc + ((size_t)b * L_SEQ + l0 + r) * D_INNER + c);
    }
    __syncthreads();

    float acc[4] = {0.f, 0.f, 0.f, 0.f};
    for (int c = 0; c < D_INNER; c += 4) {
        const float4 wv = *(const float4*)&W[(size_t)t * D_INNER + c];
#pragma unroll
        for (int r = 0; r < 4; ++r) {
            acc[r] = fmaf(wv.x, yr[r][c],
                     fmaf(wv.y, yr[r][c + 1],
                     fmaf(wv.z, yr[r][c + 2],
                     fmaf(wv.w, yr[r][c + 3], acc[r]))));
        }
    }
    const size_t ob = ((size_t)b * DIM + t) * L_SEQ + l0;
#pragma unroll
    for (int r = 0; r < 4; ++r)
        out[ob + r] = x[ob + r] + acc[r];
}

// ---------------------------------------------------------------------------
extern "C" void kernel_launch(void* const* d_in, const int* in_sizes, int n_in,
                              void* d_out, int out_size, void* d_ws, size_t ws_size,
                              hipStream_t stream)
{
    const float* x       = (const float*)d_in[0];
    const float* ln_w    = (const float*)d_in[1];
    const float* ln_b    = (const float*)d_in[2];
    const float* in_proj = (const float*)d_in[3];
    // per-direction params: f = 4..9, b = 10..15, s = 16..21
    const float* conv_w[3] = {(const float*)d_in[4],  (const float*)d_in[10], (const float*)d_in[16]};
    const float* conv_b[3] = {(const float*)d_in[5],  (const float*)d_in[11], (const float*)d_in[17]};
    const float* xpw[3]    = {(const float*)d_in[6],  (const float*)d_in[12], (const float*)d_in[18]};
    const float* dtw[3]    = {(const float*)d_in[7],  (const float*)d_in[13], (const float*)d_in[19]};
    const float* dtb[3]    = {(const float*)d_in[8],  (const float*)d_in[14], (const float*)d_in[20]};
    const float* Dp[3]     = {(const float*)d_in[9],  (const float*)d_in[15], (const float*)d_in[21]};
    const float* A_log[3]  = {(const float*)d_in[22], (const float*)d_in[23], (const float*)d_in[24]};
    const float* out_proj  = (const float*)d_in[25];
    float* out = (float*)d_out;

    // workspace layout (floats)
    const size_t NROW = (size_t)B_SZ * L_SEQ;       // 8192
    const size_t SZ_BIG = NROW * D_INNER;           // 4,194,304 floats (16 MB)
    float* ws   = (float*)d_ws;
    float* xin  = ws;                               // 16 MB
    float* sz   = xin + SZ_BIG;                     // 16 MB
    float* yacc = sz + SZ_BIG;                      // 16 MB
    float* xc   = yacc + SZ_BIG;                    // 16 MB
    float* dt   = xc + SZ_BIG;                      // 16 MB
    float* bc   = dt + SZ_BIG;                      // 1 MB
    (void)ws_size; (void)in_sizes; (void)n_in; (void)out_size;

    // 1) LN + in_proj
    k_ln_inproj<<<dim3(B_SZ * L_SEQ / 4), dim3(256), 0, stream>>>(
        x, ln_w, ln_b, in_proj, xin, sz);

    // 2) per-direction pipeline (sequential; buffers reused)
    for (int dir = 0; dir < 3; ++dir) {
        k_conv<<<dim3(B_SZ * L_SEQ * 2), dim3(256), 0, stream>>>(
            xin, conv_w[dir], conv_b[dir], xc, dir);
        k_proj<<<dim3(B_SZ * L_SEQ), dim3(256), 0, stream>>>(
            xc, xpw[dir], dtw[dir], dtb[dir], dt, bc);
        k_scan<<<dim3(B_SZ * 32), dim3(256), 0, stream>>>(
            dt, xc, bc, A_log[dir], Dp[dir], sz, yacc, dir, dir > 0 ? 1 : 0);
    }

    // 3) out_proj + residual
    k_out<<<dim3(B_SZ * L_SEQ / 4), dim3(256), 0, stream>>>(
        yacc, out_proj, x, out);
}

// Round 2
// 821.413 us; speedup vs baseline: 4.6021x; 4.6021x over previous
//
#include <hip/hip_runtime.h>
#include <hip/hip_bf16.h>
#include <cstdint>

#define B_SZ 2
#define DIM 256
#define L_SEQ 4096
#define D_INNER 512
#define DT_RANK 16
#define D_STATE 16
#define NCHUNK 32
#define CHUNK 128

__device__ __forceinline__ float silu_f(float v) {
    return v / (1.0f + __expf(-v));
}
__device__ __forceinline__ float softplus_f(float v) {
    return (v > 20.0f) ? v : log1pf(__expf(v));
}
// direction map: sequence position p -> original flat index l
__device__ __forceinline__ int dir_map(int p, int dirmode) {
    if (dirmode == 0) return p;
    if (dirmode == 1) return (L_SEQ - 1) - p;
    return ((p & 63) << 6) | (p >> 6);   // 64x64 transpose
}

// ---------------------------------------------------------------------------
// Kernel 1: LayerNorm over channels + in_proj GEMM (8192 x 1024, K=256).
// Block = 8 rows. Wave w does LN of rows 2w, 2w+1. Proj: thread t computes
// outputs j = t + 256*jj for all 8 rows.
// ---------------------------------------------------------------------------
__global__ __launch_bounds__(256) void k_ln_inproj(
    const float* __restrict__ x, const float* __restrict__ lnw,
    const float* __restrict__ lnb, const float* __restrict__ W,
    float* __restrict__ xin, float* __restrict__ sz)
{
    __shared__ float xn[8][DIM];
    const int b  = blockIdx.x >> 9;             // 512 blocks per batch
    const int l0 = (blockIdx.x & 511) << 3;
    const int t  = threadIdx.x;
    const int wave = t >> 6, lane = t & 63;

    const float* xb = x + (size_t)b * DIM * L_SEQ;
#pragma unroll
    for (int rr = 0; rr < 2; ++rr) {
        const int r = wave * 2 + rr;
        const int l = l0 + r;
        float v[4];
        float sum = 0.f, sq = 0.f;
#pragma unroll
        for (int k = 0; k < 4; ++k) {
            const int c = lane + 64 * k;
            v[k] = xb[(size_t)c * L_SEQ + l];
            sum += v[k];
            sq  += v[k] * v[k];
        }
#pragma unroll
        for (int m = 32; m >= 1; m >>= 1) {
            sum += __shfl_xor(sum, m);
            sq  += __shfl_xor(sq, m);
        }
        const float mu   = sum * (1.0f / DIM);
        const float var  = sq * (1.0f / DIM) - mu * mu;
        const float rstd = rsqrtf(var + 1e-5f);
#pragma unroll
        for (int k = 0; k < 4; ++k) {
            const int c = lane + 64 * k;
            xn[r][c] = (v[k] - mu) * rstd * lnw[c] + lnb[c];
        }
    }
    __syncthreads();

    float acc[4][8];
#pragma unroll
    for (int jj = 0; jj < 4; ++jj)
#pragma unroll
        for (int r = 0; r < 8; ++r) acc[jj][r] = 0.f;

    for (int c = 0; c < DIM; c += 4) {
        float4 xv[8];
#pragma unroll
        for (int r = 0; r < 8; ++r) xv[r] = *(const float4*)&xn[r][c];
#pragma unroll
        for (int jj = 0; jj < 4; ++jj) {
            const int j = t + 256 * jj;
            const float4 wv = *(const float4*)&W[(size_t)j * DIM + c];
#pragma unroll
            for (int r = 0; r < 8; ++r) {
                acc[jj][r] = fmaf(wv.x, xv[r].x,
                             fmaf(wv.y, xv[r].y,
                             fmaf(wv.z, xv[r].z,
                             fmaf(wv.w, xv[r].w, acc[jj][r]))));
            }
        }
    }
#pragma unroll
    for (int jj = 0; jj < 4; ++jj) {
        const int j = t + 256 * jj;
#pragma unroll
        for (int r = 0; r < 8; ++r) {
            const size_t row = (size_t)b * L_SEQ + (l0 + r);
            if (j < D_INNER) xin[row * D_INNER + j] = acc[jj][r];
            else             sz[row * D_INNER + (j - D_INNER)] = silu_f(acc[jj][r]);
        }
    }
}

// ---------------------------------------------------------------------------
// Kernel 2: causal depthwise conv (K=4) + SiLU into sequence order.
// ---------------------------------------------------------------------------
__global__ __launch_bounds__(256) void k_conv(
    const float* __restrict__ xin, const float* __restrict__ cw,
    const float* __restrict__ cb, float* __restrict__ xc, int dirmode)
{
    const int gid = blockIdx.x;              // B * L * 2
    const int b   = gid >> 13;
    const int rem = gid & 8191;
    const int p   = rem >> 1;
    const int d   = ((rem & 1) << 8) + threadIdx.x;

    float acc = cb[d];
#pragma unroll
    for (int k = 0; k < 4; ++k) {
        const int pk = p - 3 + k;
        if (pk < 0) continue;
        const int lo = dir_map(pk, dirmode);
        acc = fmaf(xin[((size_t)b * L_SEQ + lo) * D_INNER + d], cw[d * 4 + k], acc);
    }
    xc[((size_t)b * L_SEQ + p) * D_INNER + d] = silu_f(acc);
}

// ---------------------------------------------------------------------------
// Kernel 3: x_proj (48 outs, K=512) + dt_proj (512 outs, K=16) + softplus.
// Block = 16 rows staged in LDS. x_proj: lane j (=t&63, j<48), row-group
// t>>6 handles 4 rows sharing one weight row (LDS broadcast reads).
// ---------------------------------------------------------------------------
__global__ __launch_bounds__(256) void k_proj(
    const float* __restrict__ xc, const float* __restrict__ xpw,
    const float* __restrict__ dtw, const float* __restrict__ dtb,
    float* __restrict__ dt, float* __restrict__ bc)
{
    const int b  = blockIdx.x >> 8;          // 256 blocks per batch
    const int p0 = (blockIdx.x & 255) << 4;
    const int t  = threadIdx.x;
    __shared__ float xrow[16][D_INNER];      // 32 KB
    __shared__ float xdbl[16][48];

    const size_t base = ((size_t)b * L_SEQ + p0) * D_INNER;
#pragma unroll
    for (int rep = 0; rep < 8; ++rep) {
        const int idx = rep * 256 + t;       // 2048 float4
        const int r = idx >> 7, c = (idx & 127) << 2;
        *(float4*)&xrow[r][c] = *(const float4*)(xc + base + (size_t)r * D_INNER + c);
    }
    __syncthreads();

    {
        const int j  = t & 63;
        const int rg = (t >> 6) << 2;
        if (j < 48) {
            float a0 = 0.f, a1 = 0.f, a2 = 0.f, a3 = 0.f;
            for (int c = 0; c < D_INNER; c += 4) {
                const float4 wv = *(const float4*)&xpw[(size_t)j * D_INNER + c];
                const float4 x0 = *(const float4*)&xrow[rg + 0][c];
                const float4 x1 = *(const float4*)&xrow[rg + 1][c];
                const float4 x2 = *(const float4*)&xrow[rg + 2][c];
                const float4 x3 = *(const float4*)&xrow[rg + 3][c];
                a0 = fmaf(wv.x, x0.x, fmaf(wv.y, x0.y, fmaf(wv.z, x0.z, fmaf(wv.w, x0.w, a0))));
                a1 = fmaf(wv.x, x1.x, fmaf(wv.y, x1.y, fmaf(wv.z, x1.z, fmaf(wv.w, x1.w, a1))));
                a2 = fmaf(wv.x, x2.x, fmaf(wv.y, x2.y, fmaf(wv.z, x2.z, fmaf(wv.w, x2.w, a2))));
                a3 = fmaf(wv.x, x3.x, fmaf(wv.y, x3.y, fmaf(wv.z, x3.z, fmaf(wv.w, x3.w, a3))));
            }
            xdbl[rg + 0][j] = a0;
            xdbl[rg + 1][j] = a1;
            xdbl[rg + 2][j] = a2;
            xdbl[rg + 3][j] = a3;
        }
    }
    __syncthreads();

#pragma unroll
    for (int jj = 0; jj < 2; ++jj) {
        const int dd = t + (jj << 8);
        const float4 w0 = *(const float4*)&dtw[dd * DT_RANK + 0];
        const float4 w1 = *(const float4*)&dtw[dd * DT_RANK + 4];
        const float4 w2 = *(const float4*)&dtw[dd * DT_RANK + 8];
        const float4 w3 = *(const float4*)&dtw[dd * DT_RANK + 12];
        const float bias = dtb[dd];
#pragma unroll 4
        for (int r = 0; r < 16; ++r) {
            float a = bias;
            a = fmaf(w0.x, xdbl[r][0],  fmaf(w0.y, xdbl[r][1],  fmaf(w0.z, xdbl[r][2],  fmaf(w0.w, xdbl[r][3],  a))));
            a = fmaf(w1.x, xdbl[r][4],  fmaf(w1.y, xdbl[r][5],  fmaf(w1.z, xdbl[r][6],  fmaf(w1.w, xdbl[r][7],  a))));
            a = fmaf(w2.x, xdbl[r][8],  fmaf(w2.y, xdbl[r][9],  fmaf(w2.z, xdbl[r][10], fmaf(w2.w, xdbl[r][11], a))));
            a = fmaf(w3.x, xdbl[r][12], fmaf(w3.y, xdbl[r][13], fmaf(w3.z, xdbl[r][14], fmaf(w3.w, xdbl[r][15], a))));
            dt[((size_t)b * L_SEQ + p0 + r) * D_INNER + dd] = softplus_f(a);
        }
    }
#pragma unroll
    for (int rep = 0; rep < 2; ++rep) {
        const int idx = rep * 256 + t;       // 512
        const int r = idx >> 5, c = idx & 31;
        bc[((size_t)b * L_SEQ + p0 + r) * 32 + c] = xdbl[r][16 + c];
    }
}

// ---------------------------------------------------------------------------
// Kernel 4a: scan phase 1 — per-chunk transition. Block = (b, chunk, dblk),
// 2048 blocks. Computes P = prod(dA), F = local final state (h0 = 0).
// ---------------------------------------------------------------------------
__global__ __launch_bounds__(256) void k_scan1(
    const float* __restrict__ dt, const float* __restrict__ xc,
    const float* __restrict__ bcbuf, const float* __restrict__ A_log,
    float* __restrict__ Pb, float* __restrict__ Fb)
{
    const int bid   = blockIdx.x;
    const int b     = bid >> 10;
    const int chunk = (bid >> 5) & 31;
    const int dblk  = bid & 31;
    const int t  = threadIdx.x;
    const int dl = t >> 4, s = t & 15;
    const int d  = dblk * 16 + dl;

    const float As = -__expf(A_log[d * D_STATE + s]);
    float P = 1.f, h = 0.f;

    __shared__ float dtc[64 * 16];
    __shared__ float xcc[64 * 16];
    __shared__ float bcb[64 * 16];

    const size_t rowbase = (size_t)b * L_SEQ + chunk * CHUNK;

    for (int sub = 0; sub < 2; ++sub) {
        const int p0 = sub * 64;
        {
            const int j = t >> 2, c4 = (t & 3) << 2;
            const size_t go = (rowbase + p0 + j) * D_INNER + dblk * 16 + c4;
            *(float4*)&dtc[j * 16 + c4] = *(const float4*)(dt + go);
            *(float4*)&xcc[j * 16 + c4] = *(const float4*)(xc + go);
            *(float4*)&bcb[j * 16 + c4] =
                *(const float4*)(bcbuf + (rowbase + p0 + j) * 32 + c4);
        }
        __syncthreads();
#pragma unroll 8
        for (int j = 0; j < 64; ++j) {
            const float dtv = dtc[j * 16 + dl];
            const float xv  = xcc[j * 16 + dl];
            const float Bv  = bcb[j * 16 + s];
            const float dA  = __expf(dtv * As);
            P *= dA;
            h = fmaf(dA, h, dtv * xv * Bv);
        }
        __syncthreads();
    }
    const size_t o = (((size_t)b * NCHUNK + chunk) * D_INNER + d) * D_STATE + s;
    Pb[o] = P;
    Fb[o] = h;
}

// ---------------------------------------------------------------------------
// Kernel 4b: sequential combine over chunks. Hin[c] = state entering chunk c.
// ---------------------------------------------------------------------------
__global__ __launch_bounds__(256) void k_comb(
    const float* __restrict__ Pb, const float* __restrict__ Fb,
    float* __restrict__ Hin)
{
    const int gid = blockIdx.x * 256 + threadIdx.x;   // 16384
    const int b   = gid >> 13;
    const int rem = gid & 8191;                       // d*16+s
    float h = 0.f;
    for (int c = 0; c < NCHUNK; ++c) {
        const size_t i = ((size_t)(b * NCHUNK + c) << 13) + rem;
        Hin[i] = h;
        h = Fb[i] + Pb[i] * h;
    }
}

// ---------------------------------------------------------------------------
// Kernel 4c: scan phase 2 — full scan per chunk with correct incoming state,
// y output, + xc*D, * silu(z), scatter through dir_map into yacc.
// ---------------------------------------------------------------------------
__global__ __launch_bounds__(256) void k_scan2(
    const float* __restrict__ dt, const float* __restrict__ xc,
    const float* __restrict__ bcbuf, const float* __restrict__ A_log,
    const float* __restrict__ Dp, const float* __restrict__ sz,
    const float* __restrict__ Hin,
    float* __restrict__ yacc, int dirmode, int accum)
{
    const int bid   = blockIdx.x;
    const int b     = bid >> 10;
    const int chunk = (bid >> 5) & 31;
    const int dblk  = bid & 31;
    const int t  = threadIdx.x;
    const int dl = t >> 4, s = t & 15;
    const int d  = dblk * 16 + dl;

    const float As = -__expf(A_log[d * D_STATE + s]);
    const float Dv = Dp[d];
    float h = Hin[(((size_t)b * NCHUNK + chunk) * D_INNER + d) * D_STATE + s];

    __shared__ float dtc[64 * 16];
    __shared__ float xcc[64 * 16];
    __shared__ float bcc[64 * 32];
    __shared__ float ybuf[64 * 16];

    const size_t rowbase = (size_t)b * L_SEQ + chunk * CHUNK;

    for (int sub = 0; sub < 2; ++sub) {
        const int p0 = sub * 64;
        {
            const int j = t >> 2, c4 = (t & 3) << 2;
            const size_t go = (rowbase + p0 + j) * D_INNER + dblk * 16 + c4;
            *(float4*)&dtc[j * 16 + c4] = *(const float4*)(dt + go);
            *(float4*)&xcc[j * 16 + c4] = *(const float4*)(xc + go);
        }
#pragma unroll
        for (int rep = 0; rep < 2; ++rep) {
            const int idx = rep * 256 + t;
            const int j = idx >> 3, c4 = (idx & 7) << 2;
            *(float4*)&bcc[j * 32 + c4] =
                *(const float4*)(bcbuf + (rowbase + p0 + j) * 32 + c4);
        }
        __syncthreads();

#pragma unroll 4
        for (int j = 0; j < 64; ++j) {
            const float dtv = dtc[j * 16 + dl];
            const float xv  = xcc[j * 16 + dl];
            const float Bv  = bcc[j * 32 + s];
            const float Cv  = bcc[j * 32 + 16 + s];
            const float dA  = __expf(dtv * As);
            h = fmaf(dA, h, dtv * xv * Bv);
            float yc = h * Cv;
            yc += __shfl_xor(yc, 1);
            yc += __shfl_xor(yc, 2);
            yc += __shfl_xor(yc, 4);
            yc += __shfl_xor(yc, 8);
            if (s == 0) ybuf[j * 16 + dl] = yc + xv * Dv;
        }
        __syncthreads();

#pragma unroll
        for (int rep = 0; rep < 4; ++rep) {
            const int e = rep * 256 + t;
            const int j = e >> 4, dl2 = e & 15;
            const int lo = dir_map(chunk * CHUNK + p0 + j, dirmode);
            const size_t o = ((size_t)b * L_SEQ + lo) * D_INNER + dblk * 16 + dl2;
            const float val = ybuf[j * 16 + dl2] * sz[o];
            if (accum) yacc[o] += val;
            else       yacc[o] = val;
        }
        __syncthreads();
    }
}

// ---------------------------------------------------------------------------
// Kernel 5: out_proj (256 outputs, K=512) + residual. Block = 8 rows.
// ---------------------------------------------------------------------------
__global__ __launch_bounds__(256) void k_out(
    const float* __restrict__ yacc, const float* __restrict__ W,
    const float* __restrict__ x, float* __restrict__ out)
{
    __shared__ float yr[8][D_INNER];   // 16 KB
    const int b  = blockIdx.x >> 9;
    const int l0 = (blockIdx.x & 511) << 3;
    const int t  = threadIdx.x;
#pragma unroll
    for (int rep = 0; rep < 4; ++rep) {
        const int idx = rep * 256 + t;          // 1024 float4
        const int r = idx >> 7, c = (idx & 127) << 2;
        *(float4*)&yr[r][c] =
            *(const float4*)(yacc + ((size_t)b * L_SEQ + l0 + r) * D_INNER + c);
    }
    __syncthreads();

    float acc[8] = {0.f, 0.f, 0.f, 0.f, 0.f, 0.f, 0.f, 0.f};
    for (int c = 0; c < D_INNER; c += 4) {
        const float4 wv = *(const float4*)&W[(size_t)t * D_INNER + c];
#pragma unroll
        for (int r = 0; r < 8; ++r) {
            acc[r] = fmaf(wv.x, yr[r][c],
                     fmaf(wv.y, yr[r][c + 1],
                     fmaf(wv.z, yr[r][c + 2],
                     fmaf(wv.w, yr[r][c + 3], acc[r]))));
        }
    }
    const size_t ob = ((size_t)b * DIM + t) * L_SEQ + l0;
#pragma unroll
    for (int r = 0; r < 8; ++r)
        out[ob + r] = x[ob + r] + acc[r];
}

// ---------------------------------------------------------------------------
extern "C" void kernel_launch(void* const* d_in, const int* in_sizes, int n_in,
                              void* d_out, int out_size, void* d_ws, size_t ws_size,
                              hipStream_t stream)
{
    const float* x       = (const float*)d_in[0];
    const float* ln_w    = (const float*)d_in[1];
    const float* ln_b    = (const float*)d_in[2];
    const float* in_proj = (const float*)d_in[3];
    const float* conv_w[3] = {(const float*)d_in[4],  (const float*)d_in[10], (const float*)d_in[16]};
    const float* conv_b[3] = {(const float*)d_in[5],  (const float*)d_in[11], (const float*)d_in[17]};
    const float* xpw[3]    = {(const float*)d_in[6],  (const float*)d_in[12], (const float*)d_in[18]};
    const float* dtw[3]    = {(const float*)d_in[7],  (const float*)d_in[13], (const float*)d_in[19]};
    const float* dtb[3]    = {(const float*)d_in[8],  (const float*)d_in[14], (const float*)d_in[20]};
    const float* Dp[3]     = {(const float*)d_in[9],  (const float*)d_in[15], (const float*)d_in[21]};
    const float* A_log[3]  = {(const float*)d_in[22], (const float*)d_in[23], (const float*)d_in[24]};
    const float* out_proj  = (const float*)d_in[25];
    float* out = (float*)d_out;

    // workspace layout (floats)
    const size_t NROW   = (size_t)B_SZ * L_SEQ;           // 8192
    const size_t SZ_BIG = NROW * D_INNER;                 // 4,194,304 (16 MB)
    const size_t SZ_PF  = (size_t)B_SZ * NCHUNK * D_INNER * D_STATE; // 524,288 (2 MB)
    float* ws   = (float*)d_ws;
    float* xin  = ws;
    float* sz   = xin  + SZ_BIG;
    float* yacc = sz   + SZ_BIG;
    float* xc   = yacc + SZ_BIG;
    float* dt   = xc   + SZ_BIG;
    float* bc   = dt   + SZ_BIG;          // NROW*32 = 1 MB
    float* Pb   = bc   + NROW * 32;
    float* Fb   = Pb   + SZ_PF;
    float* Hin  = Fb   + SZ_PF;
    (void)ws_size; (void)in_sizes; (void)n_in; (void)out_size;

    k_ln_inproj<<<dim3(B_SZ * L_SEQ / 8), dim3(256), 0, stream>>>(
        x, ln_w, ln_b, in_proj, xin, sz);

    for (int dir = 0; dir < 3; ++dir) {
        k_conv<<<dim3(B_SZ * L_SEQ * 2), dim3(256), 0, stream>>>(
            xin, conv_w[dir], conv_b[dir], xc, dir);
        k_proj<<<dim3(B_SZ * L_SEQ / 16), dim3(256), 0, stream>>>(
            xc, xpw[dir], dtw[dir], dtb[dir], dt, bc);
        k_scan1<<<dim3(B_SZ * NCHUNK * 32), dim3(256), 0, stream>>>(
            dt, xc, bc, A_log[dir], Pb, Fb);
        k_comb<<<dim3(B_SZ * D_INNER * D_STATE / 256), dim3(256), 0, stream>>>(
            Pb, Fb, Hin);
        k_scan2<<<dim3(B_SZ * NCHUNK * 32), dim3(256), 0, stream>>>(
            dt, xc, bc, A_log[dir], Dp[dir], sz, Hin, yacc, dir, dir > 0 ? 1 : 0);
    }

    k_out<<<dim3(B_SZ * L_SEQ / 8), dim3(256), 0, stream>>>(
        yacc, out_proj, x, out);
}

// Round 3
// 633.242 us; speedup vs baseline: 5.9697x; 1.2972x over previous
//
#include <hip/hip_runtime.h>
#include <hip/hip_bf16.h>
#include <cstdint>

#define B_SZ 2
#define DIM 256
#define L_SEQ 4096
#define D_INNER 512
#define DT_RANK 16
#define D_STATE 16
#define NCHUNK 32
#define CHUNK 128

__device__ __forceinline__ float silu_f(float v) {
    return v / (1.0f + __expf(-v));
}
__device__ __forceinline__ float softplus_f(float v) {
    return (v > 20.0f) ? v : log1pf(__expf(v));
}
// direction map: sequence position p -> original flat index l (involutions)
__device__ __forceinline__ int dir_map(int p, int dm) {
    if (dm == 0) return p;
    if (dm == 1) return (L_SEQ - 1) - p;
    return ((p & 63) << 6) | (p >> 6);   // 64x64 transpose
}

// ---------------------------------------------------------------------------
// Kernel 1a: LayerNorm -> xn (fp32, [8192][256]). Block = 8 rows.
// ---------------------------------------------------------------------------
__global__ __launch_bounds__(256) void k_ln(
    const float* __restrict__ x, const float* __restrict__ lnw,
    const float* __restrict__ lnb, float* __restrict__ xn)
{
    const int b  = blockIdx.x >> 9;
    const int l0 = (blockIdx.x & 511) << 3;
    const int t  = threadIdx.x;
    const int wave = t >> 6, lane = t & 63;
    const float* xb = x + (size_t)b * DIM * L_SEQ;
#pragma unroll
    for (int rr = 0; rr < 2; ++rr) {
        const int l = l0 + wave * 2 + rr;
        float v[4];
        float sum = 0.f, sq = 0.f;
#pragma unroll
        for (int k = 0; k < 4; ++k) {
            const int c = lane + 64 * k;
            v[k] = xb[(size_t)c * L_SEQ + l];
            sum += v[k]; sq += v[k] * v[k];
        }
#pragma unroll
        for (int m = 32; m >= 1; m >>= 1) {
            sum += __shfl_xor(sum, m);
            sq  += __shfl_xor(sq, m);
        }
        const float mu   = sum * (1.0f / DIM);
        const float var  = sq * (1.0f / DIM) - mu * mu;
        const float rstd = rsqrtf(var + 1e-5f);
#pragma unroll
        for (int k = 0; k < 4; ++k) {
            const int c = lane + 64 * k;
            xn[((size_t)b * L_SEQ + l) * DIM + c] = (v[k] - mu) * rstd * lnw[c] + lnb[c];
        }
    }
}

// ---------------------------------------------------------------------------
// Kernel 1b: in_proj GEMM (8192 x 1024, K=256), weights in registers.
// Grid = 16 j-slices (64 j) x 64 row-groups (128 rows). Thread: j = t&63,
// K-quarter q = wave id (wave-uniform -> scalar loads of xn row slices).
// ---------------------------------------------------------------------------
__global__ __launch_bounds__(256) void k_inproj(
    const float* __restrict__ xn, const float* __restrict__ W,
    float* __restrict__ xin, float* __restrict__ sz)
{
    const int js = blockIdx.x & 15;
    const int rg = blockIdx.x >> 4;
    const int t  = threadIdx.x;
    const int j  = t & 63;
    const int q  = __builtin_amdgcn_readfirstlane(t >> 6);
    __shared__ float red[4][16][64];   // 16 KB

    float w[64];
    {
        const float* wp = W + (size_t)(js * 64 + j) * DIM + q * 64;
#pragma unroll
        for (int k4 = 0; k4 < 16; ++k4) {
            const float4 wv = *(const float4*)(wp + k4 * 4);
            w[k4 * 4 + 0] = wv.x; w[k4 * 4 + 1] = wv.y;
            w[k4 * 4 + 2] = wv.z; w[k4 * 4 + 3] = wv.w;
        }
    }
    const int row0 = rg * 128;
    const int col  = js * 64 + j;

    for (int g = 0; g < 8; ++g) {
        float acc[16];
#pragma unroll
        for (int r = 0; r < 16; ++r) acc[r] = 0.f;
        const float* xr0 = xn + (size_t)(row0 + g * 16) * DIM + q * 64;
#pragma unroll
        for (int r = 0; r < 16; ++r) {
            const float* xr = xr0 + (size_t)r * DIM;
#pragma unroll
            for (int kk = 0; kk < 64; ++kk)
                acc[r] = fmaf(xr[kk], w[kk], acc[r]);
        }
#pragma unroll
        for (int r = 0; r < 16; ++r) red[q][r][j] = acc[r];
        __syncthreads();
#pragma unroll
        for (int rr = 0; rr < 4; ++rr) {
            const int r = (t >> 6) + rr * 4;
            const float v = red[0][r][j] + red[1][r][j] + red[2][r][j] + red[3][r][j];
            const size_t row = row0 + g * 16 + r;
            if (col < D_INNER) xin[row * D_INNER + col] = v;
            else               sz[row * D_INNER + (col - D_INNER)] = silu_f(v);
        }
        __syncthreads();
    }
}

// ---------------------------------------------------------------------------
// Kernel 2: causal conv (K=4) + SiLU, tiled 16 positions/block, all dirs.
// Grid = ndir * B * 256. LDS-staged 19 input rows.
// ---------------------------------------------------------------------------
__global__ __launch_bounds__(256) void k_conv3(
    const float* __restrict__ xin,
    const float* __restrict__ cw0, const float* __restrict__ cw1, const float* __restrict__ cw2,
    const float* __restrict__ cb0, const float* __restrict__ cb1, const float* __restrict__ cb2,
    float* __restrict__ xcb, int dir_base, size_t big_str)
{
    const int rel = blockIdx.x >> 9;         // 512 blocks per dir
    const int rem = blockIdx.x & 511;
    const int dir = dir_base + rel;
    const int b   = rem >> 8;
    const int p0  = (rem & 255) << 4;
    const int t   = threadIdx.x;

    const float* cw = dir == 0 ? cw0 : (dir == 1 ? cw1 : cw2);
    const float* cb = dir == 0 ? cb0 : (dir == 1 ? cb1 : cb2);
    float* xc = xcb + (size_t)rel * big_str;

    __shared__ float s[19][D_INNER];   // 38 KB
    for (int i = 0; i < 19; ++i) {
        const int pk = p0 - 3 + i;
        float v0 = 0.f, v1 = 0.f;
        if (pk >= 0) {
            const int lo = dir_map(pk, dir);
            const float* src = xin + ((size_t)b * L_SEQ + lo) * D_INNER;
            v0 = src[t]; v1 = src[t + 256];
        }
        s[i][t] = v0; s[i][t + 256] = v1;
    }
    __syncthreads();

#pragma unroll
    for (int half = 0; half < 2; ++half) {
        const int d = half * 256 + t;
        const float4 wv = *(const float4*)(cw + d * 4);
        const float bb = cb[d];
#pragma unroll 4
        for (int i = 0; i < 16; ++i) {
            const float a = bb + wv.x * s[i][d] + wv.y * s[i + 1][d]
                               + wv.z * s[i + 2][d] + wv.w * s[i + 3][d];
            xc[((size_t)b * L_SEQ + p0 + i) * D_INNER + d] = silu_f(a);
        }
    }
}

// ---------------------------------------------------------------------------
// Kernel 3: x_proj (48 outs, K=512) + dt_proj (512 outs, K=16) + softplus.
// Block = 16 rows; all dirs in grid.
// ---------------------------------------------------------------------------
__global__ __launch_bounds__(256) void k_proj3(
    const float* __restrict__ xcb,
    const float* __restrict__ xpw0, const float* __restrict__ xpw1, const float* __restrict__ xpw2,
    const float* __restrict__ dtw0, const float* __restrict__ dtw1, const float* __restrict__ dtw2,
    const float* __restrict__ dtb0, const float* __restrict__ dtb1, const float* __restrict__ dtb2,
    float* __restrict__ dtbuf, float* __restrict__ bcbuf,
    int dir_base, size_t big_str, size_t bc_str)
{
    const int rel = blockIdx.x >> 9;         // 512 blocks per dir
    const int rem = blockIdx.x & 511;
    const int dir = dir_base + rel;
    const int b   = rem >> 8;
    const int p0  = (rem & 255) << 4;
    const int t   = threadIdx.x;

    const float* xc  = xcb   + (size_t)rel * big_str;
    float* dt        = dtbuf + (size_t)rel * big_str;
    float* bc        = bcbuf + (size_t)rel * bc_str;
    const float* xpw = dir == 0 ? xpw0 : (dir == 1 ? xpw1 : xpw2);
    const float* dtw = dir == 0 ? dtw0 : (dir == 1 ? dtw1 : dtw2);
    const float* dtb = dir == 0 ? dtb0 : (dir == 1 ? dtb1 : dtb2);

    __shared__ float xrow[16][D_INNER];      // 32 KB
    __shared__ float xdbl[16][48];

    const size_t base = ((size_t)b * L_SEQ + p0) * D_INNER;
#pragma unroll
    for (int rep = 0; rep < 8; ++rep) {
        const int idx = rep * 256 + t;
        const int r = idx >> 7, c = (idx & 127) << 2;
        *(float4*)&xrow[r][c] = *(const float4*)(xc + base + (size_t)r * D_INNER + c);
    }
    __syncthreads();

    {
        const int j  = t & 63;
        const int rg = (t >> 6) << 2;
        if (j < 48) {
            float a0 = 0.f, a1 = 0.f, a2 = 0.f, a3 = 0.f;
            for (int c = 0; c < D_INNER; c += 4) {
                const float4 wv = *(const float4*)&xpw[(size_t)j * D_INNER + c];
                const float4 x0 = *(const float4*)&xrow[rg + 0][c];
                const float4 x1 = *(const float4*)&xrow[rg + 1][c];
                const float4 x2 = *(const float4*)&xrow[rg + 2][c];
                const float4 x3 = *(const float4*)&xrow[rg + 3][c];
                a0 = fmaf(wv.x, x0.x, fmaf(wv.y, x0.y, fmaf(wv.z, x0.z, fmaf(wv.w, x0.w, a0))));
                a1 = fmaf(wv.x, x1.x, fmaf(wv.y, x1.y, fmaf(wv.z, x1.z, fmaf(wv.w, x1.w, a1))));
                a2 = fmaf(wv.x, x2.x, fmaf(wv.y, x2.y, fmaf(wv.z, x2.z, fmaf(wv.w, x2.w, a2))));
                a3 = fmaf(wv.x, x3.x, fmaf(wv.y, x3.y, fmaf(wv.z, x3.z, fmaf(wv.w, x3.w, a3))));
            }
            xdbl[rg + 0][j] = a0; xdbl[rg + 1][j] = a1;
            xdbl[rg + 2][j] = a2; xdbl[rg + 3][j] = a3;
        }
    }
    __syncthreads();

#pragma unroll
    for (int jj = 0; jj < 2; ++jj) {
        const int dd = t + (jj << 8);
        const float4 w0 = *(const float4*)&dtw[dd * DT_RANK + 0];
        const float4 w1 = *(const float4*)&dtw[dd * DT_RANK + 4];
        const float4 w2 = *(const float4*)&dtw[dd * DT_RANK + 8];
        const float4 w3 = *(const float4*)&dtw[dd * DT_RANK + 12];
        const float bias = dtb[dd];
#pragma unroll 4
        for (int r = 0; r < 16; ++r) {
            float a = bias;
            a = fmaf(w0.x, xdbl[r][0],  fmaf(w0.y, xdbl[r][1],  fmaf(w0.z, xdbl[r][2],  fmaf(w0.w, xdbl[r][3],  a))));
            a = fmaf(w1.x, xdbl[r][4],  fmaf(w1.y, xdbl[r][5],  fmaf(w1.z, xdbl[r][6],  fmaf(w1.w, xdbl[r][7],  a))));
            a = fmaf(w2.x, xdbl[r][8],  fmaf(w2.y, xdbl[r][9],  fmaf(w2.z, xdbl[r][10], fmaf(w2.w, xdbl[r][11], a))));
            a = fmaf(w3.x, xdbl[r][12], fmaf(w3.y, xdbl[r][13], fmaf(w3.z, xdbl[r][14], fmaf(w3.w, xdbl[r][15], a))));
            dt[((size_t)b * L_SEQ + p0 + r) * D_INNER + dd] = softplus_f(a);
        }
    }
#pragma unroll
    for (int rep = 0; rep < 2; ++rep) {
        const int idx = rep * 256 + t;
        const int r = idx >> 5, c = idx & 31;
        bc[((size_t)b * L_SEQ + p0 + r) * 32 + c] = xdbl[r][16 + c];
    }
}

// ---------------------------------------------------------------------------
// Kernel 4a: per-chunk transition (P = prod dA, F = local final state).
// ---------------------------------------------------------------------------
__global__ __launch_bounds__(256) void k_scan1(
    const float* __restrict__ dtbuf, const float* __restrict__ xcb,
    const float* __restrict__ bcbuf,
    const float* __restrict__ Al0, const float* __restrict__ Al1, const float* __restrict__ Al2,
    float* __restrict__ Pbb, float* __restrict__ Fbb,
    int dir_base, size_t big_str, size_t bc_str, size_t pf_str)
{
    const int rel = blockIdx.x >> 11;        // 2048 per dir
    const int rem = blockIdx.x & 2047;
    const int dir = dir_base + rel;
    const int b     = rem >> 10;
    const int chunk = (rem >> 5) & 31;
    const int dblk  = rem & 31;
    const int t  = threadIdx.x;
    const int dl = t >> 4, s = t & 15;
    const int d  = dblk * 16 + dl;

    const float* dt = dtbuf + (size_t)rel * big_str;
    const float* xc = xcb   + (size_t)rel * big_str;
    const float* bc = bcbuf + (size_t)rel * bc_str;
    const float* Al = dir == 0 ? Al0 : (dir == 1 ? Al1 : Al2);
    float* Pb = Pbb + (size_t)rel * pf_str;
    float* Fb = Fbb + (size_t)rel * pf_str;

    const float As = -__expf(Al[d * D_STATE + s]);
    float P = 1.f, h = 0.f;

    __shared__ float dtc[64 * 16];
    __shared__ float xcc[64 * 16];
    __shared__ float bcb[64 * 16];

    const size_t rowbase = (size_t)b * L_SEQ + chunk * CHUNK;

    for (int sub = 0; sub < 2; ++sub) {
        const int p0 = sub * 64;
        {
            const int j = t >> 2, c4 = (t & 3) << 2;
            const size_t go = (rowbase + p0 + j) * D_INNER + dblk * 16 + c4;
            *(float4*)&dtc[j * 16 + c4] = *(const float4*)(dt + go);
            *(float4*)&xcc[j * 16 + c4] = *(const float4*)(xc + go);
            *(float4*)&bcb[j * 16 + c4] =
                *(const float4*)(bc + (rowbase + p0 + j) * 32 + c4);
        }
        __syncthreads();
#pragma unroll 8
        for (int j = 0; j < 64; ++j) {
            const float dtv = dtc[j * 16 + dl];
            const float xv  = xcc[j * 16 + dl];
            const float Bv  = bcb[j * 16 + s];
            const float dA  = __expf(dtv * As);
            P *= dA;
            h = fmaf(dA, h, dtv * xv * Bv);
        }
        __syncthreads();
    }
    const size_t o = (((size_t)b * NCHUNK + chunk) * D_INNER + d) * D_STATE + s;
    Pb[o] = P;
    Fb[o] = h;
}

// ---------------------------------------------------------------------------
// Kernel 4b: sequential combine over chunks.
// ---------------------------------------------------------------------------
__global__ __launch_bounds__(256) void k_comb(
    const float* __restrict__ Pbb, const float* __restrict__ Fbb,
    float* __restrict__ Hinb, size_t pf_str)
{
    const int rel = blockIdx.x >> 6;         // 64 blocks per dir
    const int gid = (blockIdx.x & 63) * 256 + threadIdx.x;   // 16384
    const int b   = gid >> 13;
    const int rem = gid & 8191;
    const float* Pb = Pbb + (size_t)rel * pf_str;
    const float* Fb = Fbb + (size_t)rel * pf_str;
    float* Hin      = Hinb + (size_t)rel * pf_str;
    float h = 0.f;
    for (int c = 0; c < NCHUNK; ++c) {
        const size_t i = ((size_t)(b * NCHUNK + c) << 13) + rem;
        Hin[i] = h;
        h = Fb[i] + Pb[i] * h;
    }
}

// ---------------------------------------------------------------------------
// Kernel 4c: full scan with incoming state; writes y (incl. +xc*D) in
// SEQUENCE order (coalesced, no scatter, no sz).
// ---------------------------------------------------------------------------
__global__ __launch_bounds__(256) void k_scan2(
    const float* __restrict__ dtbuf, const float* __restrict__ xcb,
    const float* __restrict__ bcbuf,
    const float* __restrict__ Al0, const float* __restrict__ Al1, const float* __restrict__ Al2,
    const float* __restrict__ Dp0, const float* __restrict__ Dp1, const float* __restrict__ Dp2,
    const float* __restrict__ Hinb,
    float* __restrict__ y0, float* __restrict__ y1, float* __restrict__ y2,
    int dir_base, size_t big_str, size_t bc_str, size_t pf_str)
{
    const int rel = blockIdx.x >> 11;
    const int rem = blockIdx.x & 2047;
    const int dir = dir_base + rel;
    const int b     = rem >> 10;
    const int chunk = (rem >> 5) & 31;
    const int dblk  = rem & 31;
    const int t  = threadIdx.x;
    const int dl = t >> 4, s = t & 15;
    const int d  = dblk * 16 + dl;

    const float* dt  = dtbuf + (size_t)rel * big_str;
    const float* xc  = xcb   + (size_t)rel * big_str;
    const float* bc  = bcbuf + (size_t)rel * bc_str;
    const float* Al  = dir == 0 ? Al0 : (dir == 1 ? Al1 : Al2);
    const float* Dpp = dir == 0 ? Dp0 : (dir == 1 ? Dp1 : Dp2);
    const float* Hin = Hinb + (size_t)rel * pf_str;
    float* y = dir == 0 ? y0 : (dir == 1 ? y1 : y2);

    const float As = -__expf(Al[d * D_STATE + s]);
    const float Dv = Dpp[d];
    float h = Hin[(((size_t)b * NCHUNK + chunk) * D_INNER + d) * D_STATE + s];

    __shared__ float dtc[64 * 16];
    __shared__ float xcc[64 * 16];
    __shared__ float bcc[64 * 32];
    __shared__ float ybuf[64 * 16];

    const size_t rowbase = (size_t)b * L_SEQ + chunk * CHUNK;

    for (int sub = 0; sub < 2; ++sub) {
        const int p0 = sub * 64;
        {
            const int j = t >> 2, c4 = (t & 3) << 2;
            const size_t go = (rowbase + p0 + j) * D_INNER + dblk * 16 + c4;
            *(float4*)&dtc[j * 16 + c4] = *(const float4*)(dt + go);
            *(float4*)&xcc[j * 16 + c4] = *(const float4*)(xc + go);
        }
#pragma unroll
        for (int rep = 0; rep < 2; ++rep) {
            const int idx = rep * 256 + t;
            const int j = idx >> 3, c4 = (idx & 7) << 2;
            *(float4*)&bcc[j * 32 + c4] =
                *(const float4*)(bc + (rowbase + p0 + j) * 32 + c4);
        }
        __syncthreads();

#pragma unroll 4
        for (int j = 0; j < 64; ++j) {
            const float dtv = dtc[j * 16 + dl];
            const float xv  = xcc[j * 16 + dl];
            const float Bv  = bcc[j * 32 + s];
            const float Cv  = bcc[j * 32 + 16 + s];
            const float dA  = __expf(dtv * As);
            h = fmaf(dA, h, dtv * xv * Bv);
            float yc = h * Cv;
            yc += __shfl_xor(yc, 1);
            yc += __shfl_xor(yc, 2);
            yc += __shfl_xor(yc, 4);
            yc += __shfl_xor(yc, 8);
            if (s == 0) ybuf[j * 16 + dl] = yc + xv * Dv;
        }
        __syncthreads();

#pragma unroll
        for (int rep = 0; rep < 4; ++rep) {
            const int e = rep * 256 + t;
            const int j = e >> 4, dl2 = e & 15;
            y[(rowbase + p0 + j) * D_INNER + dblk * 16 + dl2] = ybuf[j * 16 + dl2];
        }
        __syncthreads();
    }
}

// ---------------------------------------------------------------------------
// Kernel 5: out_proj (256 outs, K=512) + residual, weights in registers.
// Stage: yt[r][c] = (y0[l] + y1[rev] + y2[T]) * sz[l]. Grid = 8 jsl x 64 rg.
// ---------------------------------------------------------------------------
__global__ __launch_bounds__(256) void k_out3(
    const float* __restrict__ y0, const float* __restrict__ y1,
    const float* __restrict__ y2, const float* __restrict__ sz,
    const float* __restrict__ W, const float* __restrict__ x,
    float* __restrict__ out)
{
    const int js = blockIdx.x & 7;           // 8 slices of 32 j
    const int rg = blockIdx.x >> 3;          // 64 row-groups of 128
    const int t  = threadIdx.x;
    const int j  = t & 31;
    const int q  = t >> 5;                   // [0,8): K-octant of 64

    __shared__ float yt[16][D_INNER];        // 32 KB
    __shared__ float red[8][16][32];         // 16 KB

    float w[64];
    {
        const float* wp = W + (size_t)(js * 32 + j) * D_INNER + q * 64;
#pragma unroll
        for (int k4 = 0; k4 < 16; ++k4) {
            const float4 wv = *(const float4*)(wp + k4 * 4);
            w[k4 * 4 + 0] = wv.x; w[k4 * 4 + 1] = wv.y;
            w[k4 * 4 + 2] = wv.z; w[k4 * 4 + 3] = wv.w;
        }
    }
    const int b  = rg >> 5;
    const int l0 = (rg & 31) * 128;
    const size_t rb = (size_t)b * L_SEQ;

    for (int g = 0; g < 8; ++g) {
#pragma unroll 2
        for (int r = 0; r < 16; ++r) {
            const int l  = l0 + g * 16 + r;
            const int p1 = (L_SEQ - 1) - l;
            const int p2 = ((l & 63) << 6) | (l >> 6);
#pragma unroll
            for (int cc = 0; cc < 2; ++cc) {
                const int c = t + cc * 256;
                const float v = y0[(rb + l)  * D_INNER + c]
                              + y1[(rb + p1) * D_INNER + c]
                              + y2[(rb + p2) * D_INNER + c];
                yt[r][c] = v * sz[(rb + l) * D_INNER + c];
            }
        }
        __syncthreads();

        float acc[16];
#pragma unroll
        for (int r = 0; r < 16; ++r) acc[r] = 0.f;
#pragma unroll
        for (int r = 0; r < 16; ++r) {
#pragma unroll
            for (int k4 = 0; k4 < 16; ++k4) {
                const float4 xv = *(const float4*)&yt[r][q * 64 + k4 * 4];
                acc[r] = fmaf(xv.x, w[k4 * 4 + 0],
                         fmaf(xv.y, w[k4 * 4 + 1],
                         fmaf(xv.z, w[k4 * 4 + 2],
                         fmaf(xv.w, w[k4 * 4 + 3], acc[r]))));
            }
        }
#pragma unroll
        for (int r = 0; r < 16; ++r) red[q][r][j] = acc[r];
        __syncthreads();

#pragma unroll
        for (int rr = 0; rr < 2; ++rr) {
            const int e  = rr * 256 + t;
            const int r  = e >> 5, j2 = e & 31;
            float v = 0.f;
#pragma unroll
            for (int q2 = 0; q2 < 8; ++q2) v += red[q2][r][j2];
            const int jo = js * 32 + j2;
            const int l  = l0 + g * 16 + r;
            const size_t o = ((size_t)b * DIM + jo) * L_SEQ + l;
            out[o] = x[o] + v;
        }
        __syncthreads();
    }
}

// ---------------------------------------------------------------------------
extern "C" void kernel_launch(void* const* d_in, const int* in_sizes, int n_in,
                              void* d_out, int out_size, void* d_ws, size_t ws_size,
                              hipStream_t stream)
{
    const float* x       = (const float*)d_in[0];
    const float* ln_w    = (const float*)d_in[1];
    const float* ln_b    = (const float*)d_in[2];
    const float* in_proj = (const float*)d_in[3];
    const float* conv_w[3] = {(const float*)d_in[4],  (const float*)d_in[10], (const float*)d_in[16]};
    const float* conv_b[3] = {(const float*)d_in[5],  (const float*)d_in[11], (const float*)d_in[17]};
    const float* xpw[3]    = {(const float*)d_in[6],  (const float*)d_in[12], (const float*)d_in[18]};
    const float* dtw[3]    = {(const float*)d_in[7],  (const float*)d_in[13], (const float*)d_in[19]};
    const float* dtb[3]    = {(const float*)d_in[8],  (const float*)d_in[14], (const float*)d_in[20]};
    const float* Dp[3]     = {(const float*)d_in[9],  (const float*)d_in[15], (const float*)d_in[21]};
    const float* A_log[3]  = {(const float*)d_in[22], (const float*)d_in[23], (const float*)d_in[24]};
    const float* out_proj  = (const float*)d_in[25];
    float* out = (float*)d_out;
    (void)in_sizes; (void)n_in; (void)out_size;

    const size_t NROW   = (size_t)B_SZ * L_SEQ;                       // 8192
    const size_t SZ_XN  = NROW * DIM;                                 // 2M
    const size_t SZ_BIG = NROW * D_INNER;                             // 4M
    const size_t SZ_BC  = NROW * 32;                                  // 256K
    const size_t SZ_PF  = (size_t)B_SZ * NCHUNK * D_INNER * D_STATE;  // 512K

    // merged mode needs: xn + xin + sz + 3*(xc+dt) + 3*bc + y1 + y2 + 3*(Pb+Fb+Hin)
    const size_t need_merged =
        SZ_XN + 2 * SZ_BIG + 6 * SZ_BIG + 3 * SZ_BC + 2 * SZ_BIG + 9 * SZ_PF;
    const bool merged = ws_size >= need_merged * sizeof(float);
    const int ndir = merged ? 3 : 1;
    const size_t big_str = merged ? SZ_BIG : 0;
    const size_t bc_str  = merged ? SZ_BC  : 0;
    const size_t pf_str  = merged ? SZ_PF  : 0;

    float* ws  = (float*)d_ws;
    float* xn  = ws;                       // dead after k_inproj
    float* xin = xn  + SZ_XN;              // dead after k_conv3 -> reused as y0
    float* sz  = xin + SZ_BIG;
    float* p   = sz + SZ_BIG;
    float* xc  = p;  p += (size_t)ndir * SZ_BIG;
    float* dt  = p;  p += (size_t)ndir * SZ_BIG;
    float* bc  = p;  p += (size_t)ndir * SZ_BC;
    float* y1  = p;  p += SZ_BIG;
    float* y2  = p;  p += SZ_BIG;
    float* Pb  = p;  p += (size_t)ndir * SZ_PF;
    float* Fb  = p;  p += (size_t)ndir * SZ_PF;
    float* Hin = p;  p += (size_t)ndir * SZ_PF;
    float* y0  = xin;                      // overlay

    k_ln<<<dim3(1024), dim3(256), 0, stream>>>(x, ln_w, ln_b, xn);
    k_inproj<<<dim3(1024), dim3(256), 0, stream>>>(xn, in_proj, xin, sz);

    for (int d0 = 0; d0 < 3; d0 += ndir) {
        k_conv3<<<dim3(512 * ndir), dim3(256), 0, stream>>>(
            xin, conv_w[0], conv_w[1], conv_w[2],
            conv_b[0], conv_b[1], conv_b[2], xc, d0, big_str);
        k_proj3<<<dim3(512 * ndir), dim3(256), 0, stream>>>(
            xc, xpw[0], xpw[1], xpw[2], dtw[0], dtw[1], dtw[2],
            dtb[0], dtb[1], dtb[2], dt, bc, d0, big_str, bc_str);
        k_scan1<<<dim3(2048 * ndir), dim3(256), 0, stream>>>(
            dt, xc, bc, A_log[0], A_log[1], A_log[2], Pb, Fb,
            d0, big_str, bc_str, pf_str);
        k_comb<<<dim3(64 * ndir), dim3(256), 0, stream>>>(Pb, Fb, Hin, pf_str);
        k_scan2<<<dim3(2048 * ndir), dim3(256), 0, stream>>>(
            dt, xc, bc, A_log[0], A_log[1], A_log[2],
            Dp[0], Dp[1], Dp[2], Hin, y0, y1, y2,
            d0, big_str, bc_str, pf_str);
    }

    k_out3<<<dim3(512), dim3(256), 0, stream>>>(
        y0, y1, y2, sz, out_proj, x, out);
}

// Round 4
// 530.251 us; speedup vs baseline: 7.1292x; 1.1942x over previous
//
#include <hip/hip_runtime.h>
#include <hip/hip_bf16.h>
#include <cstdint>

#define B_SZ 2
#define DIM 256
#define L_SEQ 4096
#define D_INNER 512
#define DT_RANK 16
#define D_STATE 16
#define NCHUNK 64
#define CHUNK 64

static constexpr size_t SZ_BIGC = (size_t)B_SZ * L_SEQ * D_INNER;  // 4M floats

__device__ __forceinline__ float silu_f(float v) {
    return v / (1.0f + __expf(-v));
}
__device__ __forceinline__ float softplus_f(float v) {
    return (v > 20.0f) ? v : log1pf(__expf(v));
}
// direction map: sequence position p -> original flat index l (involutions)
__device__ __forceinline__ int dir_map(int p, int dm) {
    if (dm == 0) return p;
    if (dm == 1) return (L_SEQ - 1) - p;
    return ((p & 63) << 6) | (p >> 6);   // 64x64 transpose
}

// ---------------------------------------------------------------------------
// Kernel 1a: LayerNorm -> xn (fp32, [8192][256]). Block = 8 rows.
// ---------------------------------------------------------------------------
__global__ __launch_bounds__(256) void k_ln(
    const float* __restrict__ x, const float* __restrict__ lnw,
    const float* __restrict__ lnb, float* __restrict__ xn)
{
    const int b  = blockIdx.x >> 9;
    const int l0 = (blockIdx.x & 511) << 3;
    const int t  = threadIdx.x;
    const int wave = t >> 6, lane = t & 63;
    const float* xb = x + (size_t)b * DIM * L_SEQ;
#pragma unroll
    for (int rr = 0; rr < 2; ++rr) {
        const int l = l0 + wave * 2 + rr;
        float v[4];
        float sum = 0.f, sq = 0.f;
#pragma unroll
        for (int k = 0; k < 4; ++k) {
            const int c = lane + 64 * k;
            v[k] = xb[(size_t)c * L_SEQ + l];
            sum += v[k]; sq += v[k] * v[k];
        }
#pragma unroll
        for (int m = 32; m >= 1; m >>= 1) {
            sum += __shfl_xor(sum, m);
            sq  += __shfl_xor(sq, m);
        }
        const float mu   = sum * (1.0f / DIM);
        const float var  = sq * (1.0f / DIM) - mu * mu;
        const float rstd = rsqrtf(var + 1e-5f);
#pragma unroll
        for (int k = 0; k < 4; ++k) {
            const int c = lane + 64 * k;
            xn[((size_t)b * L_SEQ + l) * DIM + c] = (v[k] - mu) * rstd * lnw[c] + lnb[c];
        }
    }
}

// ---------------------------------------------------------------------------
// Kernel 1b: in_proj GEMM (8192 x 1024, K=256), weights in registers.
// ---------------------------------------------------------------------------
__global__ __launch_bounds__(256) void k_inproj(
    const float* __restrict__ xn, const float* __restrict__ W,
    float* __restrict__ xin, float* __restrict__ sz)
{
    const int js = blockIdx.x & 15;
    const int rg = blockIdx.x >> 4;
    const int t  = threadIdx.x;
    const int j  = t & 63;
    const int q  = __builtin_amdgcn_readfirstlane(t >> 6);
    __shared__ float red[4][16][64];   // 16 KB

    float w[64];
    {
        const float* wp = W + (size_t)(js * 64 + j) * DIM + q * 64;
#pragma unroll
        for (int k4 = 0; k4 < 16; ++k4) {
            const float4 wv = *(const float4*)(wp + k4 * 4);
            w[k4 * 4 + 0] = wv.x; w[k4 * 4 + 1] = wv.y;
            w[k4 * 4 + 2] = wv.z; w[k4 * 4 + 3] = wv.w;
        }
    }
    const int row0 = rg * 128;
    const int col  = js * 64 + j;

    for (int g = 0; g < 8; ++g) {
        float acc[16];
#pragma unroll
        for (int r = 0; r < 16; ++r) acc[r] = 0.f;
        const float* xr0 = xn + (size_t)(row0 + g * 16) * DIM + q * 64;
#pragma unroll
        for (int r = 0; r < 16; ++r) {
            const float* xr = xr0 + (size_t)r * DIM;
#pragma unroll
            for (int kk = 0; kk < 64; ++kk)
                acc[r] = fmaf(xr[kk], w[kk], acc[r]);
        }
#pragma unroll
        for (int r = 0; r < 16; ++r) red[q][r][j] = acc[r];
        __syncthreads();
#pragma unroll
        for (int rr = 0; rr < 4; ++rr) {
            const int r = (t >> 6) + rr * 4;
            const float v = red[0][r][j] + red[1][r][j] + red[2][r][j] + red[3][r][j];
            const size_t row = row0 + g * 16 + r;
            if (col < D_INNER) xin[row * D_INNER + col] = v;
            else               sz[row * D_INNER + (col - D_INNER)] = silu_f(v);
        }
        __syncthreads();
    }
}

// ---------------------------------------------------------------------------
// Kernel 2: causal conv (K=4) + SiLU, tiled 16 positions/block, all dirs.
// ---------------------------------------------------------------------------
__global__ __launch_bounds__(256) void k_conv3(
    const float* __restrict__ xin,
    const float* __restrict__ cw0, const float* __restrict__ cw1, const float* __restrict__ cw2,
    const float* __restrict__ cb0, const float* __restrict__ cb1, const float* __restrict__ cb2,
    float* __restrict__ xcb, int dir_base, size_t big_str)
{
    const int rel = blockIdx.x >> 9;         // 512 blocks per dir
    const int rem = blockIdx.x & 511;
    const int dir = dir_base + rel;
    const int b   = rem >> 8;
    const int p0  = (rem & 255) << 4;
    const int t   = threadIdx.x;

    const float* cw = dir == 0 ? cw0 : (dir == 1 ? cw1 : cw2);
    const float* cb = dir == 0 ? cb0 : (dir == 1 ? cb1 : cb2);
    float* xc = xcb + (size_t)rel * big_str;

    __shared__ float s[19][D_INNER];   // 38 KB
    for (int i = 0; i < 19; ++i) {
        const int pk = p0 - 3 + i;
        float v0 = 0.f, v1 = 0.f;
        if (pk >= 0) {
            const int lo = dir_map(pk, dir);
            const float* src = xin + ((size_t)b * L_SEQ + lo) * D_INNER;
            v0 = src[t]; v1 = src[t + 256];
        }
        s[i][t] = v0; s[i][t + 256] = v1;
    }
    __syncthreads();

#pragma unroll
    for (int half = 0; half < 2; ++half) {
        const int d = half * 256 + t;
        const float4 wv = *(const float4*)(cw + d * 4);
        const float bb = cb[d];
#pragma unroll 4
        for (int i = 0; i < 16; ++i) {
            const float a = bb + wv.x * s[i][d] + wv.y * s[i + 1][d]
                               + wv.z * s[i + 2][d] + wv.w * s[i + 3][d];
            xc[((size_t)b * L_SEQ + p0 + i) * D_INNER + d] = silu_f(a);
        }
    }
}

// ---------------------------------------------------------------------------
// Kernel 3: x_proj (48 outs, K=512) + dt_proj (512 outs, K=16) + softplus.
// dt is written into dtY[dir] (absolute dir indexing; later aliased by y).
// ---------------------------------------------------------------------------
__global__ __launch_bounds__(256) void k_proj3(
    const float* __restrict__ xcb,
    const float* __restrict__ xpw0, const float* __restrict__ xpw1, const float* __restrict__ xpw2,
    const float* __restrict__ dtw0, const float* __restrict__ dtw1, const float* __restrict__ dtw2,
    const float* __restrict__ dtb0, const float* __restrict__ dtb1, const float* __restrict__ dtb2,
    float* __restrict__ dtY, float* __restrict__ bcbuf,
    int dir_base, size_t big_str, size_t bc_str)
{
    const int rel = blockIdx.x >> 9;         // 512 blocks per dir
    const int rem = blockIdx.x & 511;
    const int dir = dir_base + rel;
    const int b   = rem >> 8;
    const int p0  = (rem & 255) << 4;
    const int t   = threadIdx.x;

    const float* xc  = xcb   + (size_t)rel * big_str;
    float* dt        = dtY   + (size_t)dir * SZ_BIGC;
    float* bc        = bcbuf + (size_t)rel * bc_str;
    const float* xpw = dir == 0 ? xpw0 : (dir == 1 ? xpw1 : xpw2);
    const float* dtw = dir == 0 ? dtw0 : (dir == 1 ? dtw1 : dtw2);
    const float* dtb = dir == 0 ? dtb0 : (dir == 1 ? dtb1 : dtb2);

    __shared__ float xrow[16][D_INNER];      // 32 KB
    __shared__ float xdbl[16][48];

    const size_t base = ((size_t)b * L_SEQ + p0) * D_INNER;
#pragma unroll
    for (int rep = 0; rep < 8; ++rep) {
        const int idx = rep * 256 + t;
        const int r = idx >> 7, c = (idx & 127) << 2;
        *(float4*)&xrow[r][c] = *(const float4*)(xc + base + (size_t)r * D_INNER + c);
    }
    __syncthreads();

    {
        const int j  = t & 63;
        const int rg = (t >> 6) << 2;
        if (j < 48) {
            float a0 = 0.f, a1 = 0.f, a2 = 0.f, a3 = 0.f;
            for (int c = 0; c < D_INNER; c += 4) {
                const float4 wv = *(const float4*)&xpw[(size_t)j * D_INNER + c];
                const float4 x0 = *(const float4*)&xrow[rg + 0][c];
                const float4 x1 = *(const float4*)&xrow[rg + 1][c];
                const float4 x2 = *(const float4*)&xrow[rg + 2][c];
                const float4 x3 = *(const float4*)&xrow[rg + 3][c];
                a0 = fmaf(wv.x, x0.x, fmaf(wv.y, x0.y, fmaf(wv.z, x0.z, fmaf(wv.w, x0.w, a0))));
                a1 = fmaf(wv.x, x1.x, fmaf(wv.y, x1.y, fmaf(wv.z, x1.z, fmaf(wv.w, x1.w, a1))));
                a2 = fmaf(wv.x, x2.x, fmaf(wv.y, x2.y, fmaf(wv.z, x2.z, fmaf(wv.w, x2.w, a2))));
                a3 = fmaf(wv.x, x3.x, fmaf(wv.y, x3.y, fmaf(wv.z, x3.z, fmaf(wv.w, x3.w, a3))));
            }
            xdbl[rg + 0][j] = a0; xdbl[rg + 1][j] = a1;
            xdbl[rg + 2][j] = a2; xdbl[rg + 3][j] = a3;
        }
    }
    __syncthreads();

#pragma unroll
    for (int jj = 0; jj < 2; ++jj) {
        const int dd = t + (jj << 8);
        const float4 w0 = *(const float4*)&dtw[dd * DT_RANK + 0];
        const float4 w1 = *(const float4*)&dtw[dd * DT_RANK + 4];
        const float4 w2 = *(const float4*)&dtw[dd * DT_RANK + 8];
        const float4 w3 = *(const float4*)&dtw[dd * DT_RANK + 12];
        const float bias = dtb[dd];
#pragma unroll 4
        for (int r = 0; r < 16; ++r) {
            float a = bias;
            a = fmaf(w0.x, xdbl[r][0],  fmaf(w0.y, xdbl[r][1],  fmaf(w0.z, xdbl[r][2],  fmaf(w0.w, xdbl[r][3],  a))));
            a = fmaf(w1.x, xdbl[r][4],  fmaf(w1.y, xdbl[r][5],  fmaf(w1.z, xdbl[r][6],  fmaf(w1.w, xdbl[r][7],  a))));
            a = fmaf(w2.x, xdbl[r][8],  fmaf(w2.y, xdbl[r][9],  fmaf(w2.z, xdbl[r][10], fmaf(w2.w, xdbl[r][11], a))));
            a = fmaf(w3.x, xdbl[r][12], fmaf(w3.y, xdbl[r][13], fmaf(w3.z, xdbl[r][14], fmaf(w3.w, xdbl[r][15], a))));
            dt[((size_t)b * L_SEQ + p0 + r) * D_INNER + dd] = softplus_f(a);
        }
    }
#pragma unroll
    for (int rep = 0; rep < 2; ++rep) {
        const int idx = rep * 256 + t;
        const int r = idx >> 5, c = idx & 31;
        bc[((size_t)b * L_SEQ + p0 + r) * 32 + c] = xdbl[r][16 + c];
    }
}

// ---------------------------------------------------------------------------
// Kernel 4a: per-chunk transition, channel-per-thread. Thread owns channel d,
// keeps h[16] in registers. P_s = exp2(As2_s * sum(dt)); F = local final h.
// Block = (dir, b, chunk, half): 256 channels, 64 steps in 4 LDS tiles.
// ---------------------------------------------------------------------------
__global__ __launch_bounds__(256) void k_scan1(
    const float* __restrict__ dtY, const float* __restrict__ xcb,
    const float* __restrict__ bcb,
    const float* __restrict__ Al0, const float* __restrict__ Al1, const float* __restrict__ Al2,
    float* __restrict__ Pbb, float* __restrict__ Fbb,
    int dir_base, size_t big_str, size_t bc_str, size_t pf_str)
{
    const int rel = blockIdx.x >> 8;         // 256 blocks per dir
    const int rem = blockIdx.x & 255;
    const int dir = dir_base + rel;
    const int b     = rem >> 7;
    const int chunk = (rem >> 1) & 63;
    const int half  = rem & 1;
    const int t = threadIdx.x;
    const int d = half * 256 + t;

    const float* dt = dtY + (size_t)dir * SZ_BIGC;
    const float* xc = xcb + (size_t)rel * big_str;
    const float* bc = bcb + (size_t)rel * bc_str;
    const float* Al = dir == 0 ? Al0 : (dir == 1 ? Al1 : Al2);
    float* Pb = Pbb + (size_t)rel * pf_str;
    float* Fb = Fbb + (size_t)rel * pf_str;

    float As2[16];
    {
        const float* ap = Al + d * D_STATE;
#pragma unroll
        for (int s4 = 0; s4 < 4; ++s4) {
            const float4 a = *(const float4*)(ap + s4 * 4);
            As2[s4 * 4 + 0] = -__expf(a.x) * 1.44269504f;
            As2[s4 * 4 + 1] = -__expf(a.y) * 1.44269504f;
            As2[s4 * 4 + 2] = -__expf(a.z) * 1.44269504f;
            As2[s4 * 4 + 3] = -__expf(a.w) * 1.44269504f;
        }
    }
    float h[16];
#pragma unroll
    for (int s = 0; s < 16; ++s) h[s] = 0.f;
    float sumdt = 0.f;

    __shared__ float dts[16][256];   // 16 KB
    __shared__ float xcs[16][256];   // 16 KB
    __shared__ float bcs[16][16];    // 1 KB

    const size_t rowbase = (size_t)b * L_SEQ + chunk * CHUNK;
    const float* dtp = dt + rowbase * D_INNER + half * 256;
    const float* xcp = xc + rowbase * D_INNER + half * 256;
    const float* bcp = bc + rowbase * 32;

    for (int tile = 0; tile < 4; ++tile) {
        const int p0 = tile * 16;
#pragma unroll
        for (int rep = 0; rep < 4; ++rep) {
            const int idx = rep * 256 + t;           // 1024 float4
            const int jr = idx >> 6, c4 = (idx & 63) << 2;
            *(float4*)&dts[jr][c4] = *(const float4*)(dtp + (size_t)(p0 + jr) * D_INNER + c4);
            *(float4*)&xcs[jr][c4] = *(const float4*)(xcp + (size_t)(p0 + jr) * D_INNER + c4);
        }
        if (t < 64) {
            const int jr = t >> 2, c4 = (t & 3) << 2;
            *(float4*)&bcs[jr][c4] = *(const float4*)(bcp + (size_t)(p0 + jr) * 32 + c4);
        }
        __syncthreads();

#pragma unroll
        for (int j = 0; j < 16; ++j) {
            const float dtv = dts[j][t];
            const float xv  = xcs[j][t];
            sumdt += dtv;
            const float dtx = dtv * xv;
            float Bv[16];
#pragma unroll
            for (int s4 = 0; s4 < 4; ++s4) {
                const float4 bb = *(const float4*)&bcs[j][s4 * 4];
                Bv[s4 * 4 + 0] = bb.x; Bv[s4 * 4 + 1] = bb.y;
                Bv[s4 * 4 + 2] = bb.z; Bv[s4 * 4 + 3] = bb.w;
            }
#pragma unroll
            for (int s = 0; s < 16; ++s)
                h[s] = fmaf(exp2f(dtv * As2[s]), h[s], dtx * Bv[s]);
        }
        __syncthreads();
    }
    const size_t o = (((size_t)b * NCHUNK + chunk) * D_INNER + d) * D_STATE;
#pragma unroll
    for (int s = 0; s < 16; ++s) {
        Pb[o + s] = exp2f(As2[s] * sumdt);
        Fb[o + s] = h[s];
    }
}

// ---------------------------------------------------------------------------
// Kernel 4b: sequential combine over 64 chunks.
// ---------------------------------------------------------------------------
__global__ __launch_bounds__(256) void k_comb(
    const float* __restrict__ Pbb, const float* __restrict__ Fbb,
    float* __restrict__ Hinb, size_t pf_str)
{
    const int rel = blockIdx.x >> 6;         // 64 blocks per dir
    const int gid = (blockIdx.x & 63) * 256 + threadIdx.x;   // 16384
    const int b   = gid >> 13;
    const int rem = gid & 8191;
    const float* Pb = Pbb + (size_t)rel * pf_str;
    const float* Fb = Fbb + (size_t)rel * pf_str;
    float* Hin      = Hinb + (size_t)rel * pf_str;
    float h = 0.f;
    for (int c = 0; c < NCHUNK; ++c) {
        const size_t i = ((size_t)(b * NCHUNK + c) << 13) + rem;
        Hin[i] = h;
        h = Fb[i] + Pb[i] * h;
    }
}

// ---------------------------------------------------------------------------
// Kernel 4c: full scan, channel-per-thread; y = h·C + xc*D written IN PLACE
// over dt (each element is consumed via LDS staging before its y is stored).
// ---------------------------------------------------------------------------
__global__ __launch_bounds__(256) void k_scan2(
    float* dty,                               // dt in, y out (same buffer!)
    const float* __restrict__ xcb, const float* __restrict__ bcb,
    const float* __restrict__ Al0, const float* __restrict__ Al1, const float* __restrict__ Al2,
    const float* __restrict__ Dp0, const float* __restrict__ Dp1, const float* __restrict__ Dp2,
    const float* __restrict__ Hinb,
    int dir_base, size_t big_str, size_t bc_str, size_t pf_str)
{
    const int rel = blockIdx.x >> 8;
    const int rem = blockIdx.x & 255;
    const int dir = dir_base + rel;
    const int b     = rem >> 7;
    const int chunk = (rem >> 1) & 63;
    const int half  = rem & 1;
    const int t = threadIdx.x;
    const int d = half * 256 + t;

    float* dt       = dty + (size_t)dir * SZ_BIGC;
    const float* xc = xcb + (size_t)rel * big_str;
    const float* bc = bcb + (size_t)rel * bc_str;
    const float* Al  = dir == 0 ? Al0 : (dir == 1 ? Al1 : Al2);
    const float* Dpp = dir == 0 ? Dp0 : (dir == 1 ? Dp1 : Dp2);
    const float* Hin = Hinb + (size_t)rel * pf_str;

    float As2[16];
    {
        const float* ap = Al + d * D_STATE;
#pragma unroll
        for (int s4 = 0; s4 < 4; ++s4) {
            const float4 a = *(const float4*)(ap + s4 * 4);
            As2[s4 * 4 + 0] = -__expf(a.x) * 1.44269504f;
            As2[s4 * 4 + 1] = -__expf(a.y) * 1.44269504f;
            As2[s4 * 4 + 2] = -__expf(a.z) * 1.44269504f;
            As2[s4 * 4 + 3] = -__expf(a.w) * 1.44269504f;
        }
    }
    const float Dv = Dpp[d];
    float h[16];
    {
        const size_t o = (((size_t)b * NCHUNK + chunk) * D_INNER + d) * D_STATE;
#pragma unroll
        for (int s4 = 0; s4 < 4; ++s4) {
            const float4 hv = *(const float4*)(Hin + o + s4 * 4);
            h[s4 * 4 + 0] = hv.x; h[s4 * 4 + 1] = hv.y;
            h[s4 * 4 + 2] = hv.z; h[s4 * 4 + 3] = hv.w;
        }
    }

    __shared__ float dts[16][256];
    __shared__ float xcs[16][256];
    __shared__ float bcs[16][32];    // B and C

    const size_t rowbase = (size_t)b * L_SEQ + chunk * CHUNK;
    float* dtp       = dt + rowbase * D_INNER + half * 256;
    const float* xcp = xc + rowbase * D_INNER + half * 256;
    const float* bcp = bc + rowbase * 32;

    for (int tile = 0; tile < 4; ++tile) {
        const int p0 = tile * 16;
#pragma unroll
        for (int rep = 0; rep < 4; ++rep) {
            const int idx = rep * 256 + t;
            const int jr = idx >> 6, c4 = (idx & 63) << 2;
            *(float4*)&dts[jr][c4] = *(const float4*)(dtp + (size_t)(p0 + jr) * D_INNER + c4);
            *(float4*)&xcs[jr][c4] = *(const float4*)(xcp + (size_t)(p0 + jr) * D_INNER + c4);
        }
        if (t < 128) {
            const int jr = t >> 3, c4 = (t & 7) << 2;
            *(float4*)&bcs[jr][c4] = *(const float4*)(bcp + (size_t)(p0 + jr) * 32 + c4);
        }
        __syncthreads();

#pragma unroll
        for (int j = 0; j < 16; ++j) {
            const float dtv = dts[j][t];
            const float xv  = xcs[j][t];
            const float dtx = dtv * xv;
            float Bv[16], Cv[16];
#pragma unroll
            for (int s4 = 0; s4 < 4; ++s4) {
                const float4 bb = *(const float4*)&bcs[j][s4 * 4];
                const float4 cc = *(const float4*)&bcs[j][16 + s4 * 4];
                Bv[s4 * 4 + 0] = bb.x; Bv[s4 * 4 + 1] = bb.y;
                Bv[s4 * 4 + 2] = bb.z; Bv[s4 * 4 + 3] = bb.w;
                Cv[s4 * 4 + 0] = cc.x; Cv[s4 * 4 + 1] = cc.y;
                Cv[s4 * 4 + 2] = cc.z; Cv[s4 * 4 + 3] = cc.w;
            }
            float y = xv * Dv;
#pragma unroll
            for (int s = 0; s < 16; ++s) {
                h[s] = fmaf(exp2f(dtv * As2[s]), h[s], dtx * Bv[s]);
                y = fmaf(h[s], Cv[s], y);
            }
            dtp[(size_t)(p0 + j) * D_INNER + t] = y;   // overwrite consumed dt
        }
        __syncthreads();
    }
}

// ---------------------------------------------------------------------------
// Kernel 5: out_proj (256 outs, K=512) + residual, weights in registers.
// ---------------------------------------------------------------------------
__global__ __launch_bounds__(256) void k_out3(
    const float* __restrict__ yall, const float* __restrict__ sz,
    const float* __restrict__ W, const float* __restrict__ x,
    float* __restrict__ out)
{
    const float* y0 = yall;
    const float* y1 = yall + SZ_BIGC;
    const float* y2 = yall + 2 * SZ_BIGC;
    const int js = blockIdx.x & 7;           // 8 slices of 32 j
    const int rg = blockIdx.x >> 3;          // 64 row-groups of 128
    const int t  = threadIdx.x;
    const int j  = t & 31;
    const int q  = t >> 5;                   // [0,8): K-octant of 64

    __shared__ float yt[16][D_INNER];        // 32 KB
    __shared__ float red[8][16][32];         // 16 KB

    float w[64];
    {
        const float* wp = W + (size_t)(js * 32 + j) * D_INNER + q * 64;
#pragma unroll
        for (int k4 = 0; k4 < 16; ++k4) {
            const float4 wv = *(const float4*)(wp + k4 * 4);
            w[k4 * 4 + 0] = wv.x; w[k4 * 4 + 1] = wv.y;
            w[k4 * 4 + 2] = wv.z; w[k4 * 4 + 3] = wv.w;
        }
    }
    const int b  = rg >> 5;
    const int l0 = (rg & 31) * 128;
    const size_t rb = (size_t)b * L_SEQ;

    for (int g = 0; g < 8; ++g) {
#pragma unroll 2
        for (int r = 0; r < 16; ++r) {
            const int l  = l0 + g * 16 + r;
            const int p1 = (L_SEQ - 1) - l;
            const int p2 = ((l & 63) << 6) | (l >> 6);
#pragma unroll
            for (int cc = 0; cc < 2; ++cc) {
                const int c = t + cc * 256;
                const float v = y0[(rb + l)  * D_INNER + c]
                              + y1[(rb + p1) * D_INNER + c]
                              + y2[(rb + p2) * D_INNER + c];
                yt[r][c] = v * sz[(rb + l) * D_INNER + c];
            }
        }
        __syncthreads();

        float acc[16];
#pragma unroll
        for (int r = 0; r < 16; ++r) acc[r] = 0.f;
#pragma unroll
        for (int r = 0; r < 16; ++r) {
#pragma unroll
            for (int k4 = 0; k4 < 16; ++k4) {
                const float4 xv = *(const float4*)&yt[r][q * 64 + k4 * 4];
                acc[r] = fmaf(xv.x, w[k4 * 4 + 0],
                         fmaf(xv.y, w[k4 * 4 + 1],
                         fmaf(xv.z, w[k4 * 4 + 2],
                         fmaf(xv.w, w[k4 * 4 + 3], acc[r]))));
            }
        }
#pragma unroll
        for (int r = 0; r < 16; ++r) red[q][r][j] = acc[r];
        __syncthreads();

#pragma unroll
        for (int rr = 0; rr < 2; ++rr) {
            const int e  = rr * 256 + t;
            const int r  = e >> 5, j2 = e & 31;
            float v = 0.f;
#pragma unroll
            for (int q2 = 0; q2 < 8; ++q2) v += red[q2][r][j2];
            const int jo = js * 32 + j2;
            const int l  = l0 + g * 16 + r;
            const size_t o = ((size_t)b * DIM + jo) * L_SEQ + l;
            out[o] = x[o] + v;
        }
        __syncthreads();
    }
}

// ---------------------------------------------------------------------------
extern "C" void kernel_launch(void* const* d_in, const int* in_sizes, int n_in,
                              void* d_out, int out_size, void* d_ws, size_t ws_size,
                              hipStream_t stream)
{
    const float* x       = (const float*)d_in[0];
    const float* ln_w    = (const float*)d_in[1];
    const float* ln_b    = (const float*)d_in[2];
    const float* in_proj = (const float*)d_in[3];
    const float* conv_w[3] = {(const float*)d_in[4],  (const float*)d_in[10], (const float*)d_in[16]};
    const float* conv_b[3] = {(const float*)d_in[5],  (const float*)d_in[11], (const float*)d_in[17]};
    const float* xpw[3]    = {(const float*)d_in[6],  (const float*)d_in[12], (const float*)d_in[18]};
    const float* dtw[3]    = {(const float*)d_in[7],  (const float*)d_in[13], (const float*)d_in[19]};
    const float* dtb[3]    = {(const float*)d_in[8],  (const float*)d_in[14], (const float*)d_in[20]};
    const float* Dp[3]     = {(const float*)d_in[9],  (const float*)d_in[15], (const float*)d_in[21]};
    const float* A_log[3]  = {(const float*)d_in[22], (const float*)d_in[23], (const float*)d_in[24]};
    const float* out_proj  = (const float*)d_in[25];
    float* out = (float*)d_out;
    (void)in_sizes; (void)n_in; (void)out_size;

    const size_t NROW   = (size_t)B_SZ * L_SEQ;                       // 8192
    const size_t SZ_XN  = NROW * DIM;                                 // 2M
    const size_t SZ_BIG = NROW * D_INNER;                             // 4M
    const size_t SZ_BC  = NROW * 32;                                  // 256K
    const size_t SZ_PF  = (size_t)B_SZ * NCHUNK * D_INNER * D_STATE;  // 1M

    // merged: xn + xin + sz + dtY(3) + 3*xc + 3*bc + 3*(Pb+Fb+Hin) = 43.75M fl
    const size_t need_merged =
        SZ_XN + 2 * SZ_BIG + 3 * SZ_BIG + 3 * SZ_BIG + 3 * SZ_BC + 9 * SZ_PF;
    const bool merged = ws_size >= need_merged * sizeof(float);
    const int ndir = merged ? 3 : 1;
    const size_t big_str = merged ? SZ_BIG : 0;
    const size_t bc_str  = merged ? SZ_BC  : 0;
    const size_t pf_str  = merged ? SZ_PF  : 0;

    float* ws  = (float*)d_ws;
    float* xn  = ws;
    float* xin = xn  + SZ_XN;
    float* sz  = xin + SZ_BIG;
    float* dtY = sz  + SZ_BIG;             // ALWAYS 3 buffers; y aliases dt
    float* p   = dtY + 3 * SZ_BIG;
    float* xc  = p;  p += (size_t)ndir * SZ_BIG;
    float* bc  = p;  p += (size_t)ndir * SZ_BC;
    float* Pb  = p;  p += (size_t)ndir * SZ_PF;
    float* Fb  = p;  p += (size_t)ndir * SZ_PF;
    float* Hin = p;  p += (size_t)ndir * SZ_PF;

    k_ln<<<dim3(1024), dim3(256), 0, stream>>>(x, ln_w, ln_b, xn);
    k_inproj<<<dim3(1024), dim3(256), 0, stream>>>(xn, in_proj, xin, sz);

    for (int d0 = 0; d0 < 3; d0 += ndir) {
        k_conv3<<<dim3(512 * ndir), dim3(256), 0, stream>>>(
            xin, conv_w[0], conv_w[1], conv_w[2],
            conv_b[0], conv_b[1], conv_b[2], xc, d0, big_str);
        k_proj3<<<dim3(512 * ndir), dim3(256), 0, stream>>>(
            xc, xpw[0], xpw[1], xpw[2], dtw[0], dtw[1], dtw[2],
            dtb[0], dtb[1], dtb[2], dtY, bc, d0, big_str, bc_str);
        k_scan1<<<dim3(256 * ndir), dim3(256), 0, stream>>>(
            dtY, xc, bc, A_log[0], A_log[1], A_log[2], Pb, Fb,
            d0, big_str, bc_str, pf_str);
        k_comb<<<dim3(64 * ndir), dim3(256), 0, stream>>>(Pb, Fb, Hin, pf_str);
        k_scan2<<<dim3(256 * ndir), dim3(256), 0, stream>>>(
            dtY, xc, bc, A_log[0], A_log[1], A_log[2],
            Dp[0], Dp[1], Dp[2], Hin, d0, big_str, bc_str, pf_str);
    }

    k_out3<<<dim3(512), dim3(256), 0, stream>>>(
        dtY, sz, out_proj, x, out);
}

// Round 5
// 376.197 us; speedup vs baseline: 10.0486x; 1.4095x over previous
//
#include <hip/hip_runtime.h>
#include <hip/hip_bf16.h>
#include <cstdint>

#define B_SZ 2
#define DIM 256
#define L_SEQ 4096
#define D_INNER 512
#define DT_RANK 16
#define D_STATE 16
#define NCHUNK 64
#define CHUNK 64

static constexpr size_t SZ_BIGC = (size_t)B_SZ * L_SEQ * D_INNER;  // 4M floats

typedef __attribute__((ext_vector_type(8))) short short8v;
typedef __attribute__((ext_vector_type(4))) short short4v;
typedef __attribute__((ext_vector_type(4))) float f32x4;

__device__ __forceinline__ float silu_f(float v) {
    return v / (1.0f + __expf(-v));
}
__device__ __forceinline__ float softplus_f(float v) {
    return (v > 20.0f) ? v : log1pf(__expf(v));
}
__device__ __forceinline__ short f2bf(float f) {   // RNE fp32 -> bf16 bits
    uint32_t u = __float_as_uint(f);
    u += 0x7fffu + ((u >> 16) & 1u);
    return (short)(u >> 16);
}
// direction map: sequence position p -> original flat index l (involutions)
__device__ __forceinline__ int dir_map(int p, int dm) {
    if (dm == 0) return p;
    if (dm == 1) return (L_SEQ - 1) - p;
    return ((p & 63) << 6) | (p >> 6);   // 64x64 transpose
}

// ---------------------------------------------------------------------------
// Kernel 0: convert in_proj_w [1024][256] and out_proj_w [256][512] to bf16.
// ---------------------------------------------------------------------------
__global__ __launch_bounds__(256) void k_cvt(
    const float* __restrict__ Wi, const float* __restrict__ Wo,
    short* __restrict__ Wib, short* __restrict__ Wob)
{
    const int idx = (blockIdx.x * 256 + threadIdx.x) * 4;
    if (idx < 1024 * 256) {
        const float4 v = *(const float4*)(Wi + idx);
        short4v p = {f2bf(v.x), f2bf(v.y), f2bf(v.z), f2bf(v.w)};
        *(short4v*)(Wib + idx) = p;
    } else {
        const int k = idx - 1024 * 256;   // < 131072
        const float4 v = *(const float4*)(Wo + k);
        short4v p = {f2bf(v.x), f2bf(v.y), f2bf(v.z), f2bf(v.w)};
        *(short4v*)(Wob + k) = p;
    }
}

// ---------------------------------------------------------------------------
// Kernel 1a: LayerNorm via LDS transpose tile; writes xn directly as bf16.
// Block = 64 l-positions x 256 channels. Grid = B_SZ * 64 = 128.
// ---------------------------------------------------------------------------
__global__ __launch_bounds__(256) void k_ln_t(
    const float* __restrict__ x, const float* __restrict__ lnw,
    const float* __restrict__ lnb, short* __restrict__ xnb)
{
    __shared__ float xt[64][257];     // 65.8 KB, pad 1 (stride 257 % 32 == 1)
    __shared__ float red[2][4][64];
    __shared__ float muS[64], rsS[64];
    __shared__ float lnwS[DIM], lnbS[DIM];

    const int b  = blockIdx.x >> 6;
    const int l0 = (blockIdx.x & 63) << 6;
    const int t  = threadIdx.x;
    lnwS[t] = lnw[t]; lnbS[t] = lnb[t];

    const float* xb = x + (size_t)b * DIM * L_SEQ + l0;
#pragma unroll
    for (int it = 0; it < 16; ++it) {
        const int idx = it * 256 + t;           // 4096 float4 chunks
        const int c = idx >> 4, pos = (idx & 15) << 2;
        const float4 v = *(const float4*)(xb + (size_t)c * L_SEQ + pos);
        xt[pos + 0][c] = v.x; xt[pos + 1][c] = v.y;
        xt[pos + 2][c] = v.z; xt[pos + 3][c] = v.w;
    }
    __syncthreads();
    {
        const int l = t & 63, cq = t >> 6;
        float sum = 0.f, sq = 0.f;
        for (int c = cq * 64; c < cq * 64 + 64; ++c) {
            const float v = xt[l][c];
            sum += v; sq += v * v;
        }
        red[0][cq][l] = sum; red[1][cq][l] = sq;
    }
    __syncthreads();
    if (t < 64) {
        const float s  = red[0][0][t] + red[0][1][t] + red[0][2][t] + red[0][3][t];
        const float q2 = red[1][0][t] + red[1][1][t] + red[1][2][t] + red[1][3][t];
        const float mu  = s * (1.0f / DIM);
        const float var = q2 * (1.0f / DIM) - mu * mu;
        muS[t] = mu; rsS[t] = rsqrtf(var + 1e-5f);
    }
    __syncthreads();
    // write: 64 l x 128 short2-chunks
#pragma unroll
    for (int it = 0; it < 32; ++it) {
        const int idx = it * 256 + t;
        const int l = idx >> 7, cp = (idx & 127) << 1;
        const float mu = muS[l], rs = rsS[l];
        short4v dummy;
        short2 p;
        p.x = f2bf((xt[l][cp + 0] - mu) * rs * lnwS[cp + 0] + lnbS[cp + 0]);
        p.y = f2bf((xt[l][cp + 1] - mu) * rs * lnwS[cp + 1] + lnbS[cp + 1]);
        *(short2*)(xnb + (size_t)((b * L_SEQ) + l0 + l) * DIM + cp) = p;
        (void)dummy;
    }
}

// ---------------------------------------------------------------------------
// Kernel 1b: in_proj via MFMA 16x16x32 bf16. M=8192, N=1024, K=256.
// Grid = 128 M-blocks x 4 N-quarters; wave w owns 16 rows; A-frags in VGPRs,
// B-frags streamed from L2-resident bf16 W (row-major [N][K] = B layout).
// ---------------------------------------------------------------------------
__global__ __launch_bounds__(256) void k_inproj_mfma(
    const short* __restrict__ xnb, const short* __restrict__ Wib,
    float* __restrict__ xin, float* __restrict__ sz)
{
    const int mblk = blockIdx.x >> 2;
    const int q    = blockIdx.x & 3;
    const int t = threadIdx.x;
    const int w = t >> 6, l = t & 63;
    const int m0 = mblk * 64 + w * 16;
    const int n0 = q * 256;
    const int lrow = l & 15, lk = l >> 4;

    short8v a[8];
    {
        const short* ap = xnb + (size_t)(m0 + lrow) * DIM + lk * 8;
#pragma unroll
        for (int kk = 0; kk < 8; ++kk)
            a[kk] = *(const short8v*)(ap + kk * 32);
    }

#pragma unroll 4
    for (int nf = 0; nf < 16; ++nf) {
        const int n = n0 + nf * 16 + lrow;
        const short* bp = Wib + (size_t)n * DIM + lk * 8;
        f32x4 acc = {0.f, 0.f, 0.f, 0.f};
#pragma unroll
        for (int kk = 0; kk < 8; ++kk)
            acc = __builtin_amdgcn_mfma_f32_16x16x32_bf16(
                a[kk], *(const short8v*)(bp + kk * 32), acc, 0, 0, 0);
        const int col = n0 + nf * 16 + lrow;
        const int r0  = m0 + lk * 4;
        if (n0 < D_INNER) {
#pragma unroll
            for (int j = 0; j < 4; ++j)
                xin[(size_t)(r0 + j) * D_INNER + col] = acc[j];
        } else {
#pragma unroll
            for (int j = 0; j < 4; ++j)
                sz[(size_t)(r0 + j) * D_INNER + (col - D_INNER)] = silu_f(acc[j]);
        }
    }
}

// ---------------------------------------------------------------------------
// Kernel 2: causal conv (K=4) + SiLU, tiled 16 positions/block, all dirs.
// ---------------------------------------------------------------------------
__global__ __launch_bounds__(256) void k_conv3(
    const float* __restrict__ xin,
    const float* __restrict__ cw0, const float* __restrict__ cw1, const float* __restrict__ cw2,
    const float* __restrict__ cb0, const float* __restrict__ cb1, const float* __restrict__ cb2,
    float* __restrict__ xcb, int dir_base, size_t big_str)
{
    const int rel = blockIdx.x >> 9;         // 512 blocks per dir
    const int rem = blockIdx.x & 511;
    const int dir = dir_base + rel;
    const int b   = rem >> 8;
    const int p0  = (rem & 255) << 4;
    const int t   = threadIdx.x;

    const float* cw = dir == 0 ? cw0 : (dir == 1 ? cw1 : cw2);
    const float* cb = dir == 0 ? cb0 : (dir == 1 ? cb1 : cb2);
    float* xc = xcb + (size_t)rel * big_str;

    __shared__ float s[19][D_INNER];   // 38 KB
    for (int i = 0; i < 19; ++i) {
        const int pk = p0 - 3 + i;
        float v0 = 0.f, v1 = 0.f;
        if (pk >= 0) {
            const int lo = dir_map(pk, dir);
            const float* src = xin + ((size_t)b * L_SEQ + lo) * D_INNER;
            v0 = src[t]; v1 = src[t + 256];
        }
        s[i][t] = v0; s[i][t + 256] = v1;
    }
    __syncthreads();

#pragma unroll
    for (int half = 0; half < 2; ++half) {
        const int d = half * 256 + t;
        const float4 wv = *(const float4*)(cw + d * 4);
        const float bb = cb[d];
#pragma unroll 4
        for (int i = 0; i < 16; ++i) {
            const float a = bb + wv.x * s[i][d] + wv.y * s[i + 1][d]
                               + wv.z * s[i + 2][d] + wv.w * s[i + 3][d];
            xc[((size_t)b * L_SEQ + p0 + i) * D_INNER + d] = silu_f(a);
        }
    }
}

// ---------------------------------------------------------------------------
// Kernel 3: x_proj (48 outs, K=512) + dt_proj (512 outs, K=16) + softplus.
// ---------------------------------------------------------------------------
__global__ __launch_bounds__(256) void k_proj3(
    const float* __restrict__ xcb,
    const float* __restrict__ xpw0, const float* __restrict__ xpw1, const float* __restrict__ xpw2,
    const float* __restrict__ dtw0, const float* __restrict__ dtw1, const float* __restrict__ dtw2,
    const float* __restrict__ dtb0, const float* __restrict__ dtb1, const float* __restrict__ dtb2,
    float* __restrict__ dtY, float* __restrict__ bcbuf,
    int dir_base, size_t big_str, size_t bc_str)
{
    const int rel = blockIdx.x >> 9;         // 512 blocks per dir
    const int rem = blockIdx.x & 511;
    const int dir = dir_base + rel;
    const int b   = rem >> 8;
    const int p0  = (rem & 255) << 4;
    const int t   = threadIdx.x;

    const float* xc  = xcb   + (size_t)rel * big_str;
    float* dt        = dtY   + (size_t)dir * SZ_BIGC;
    float* bc        = bcbuf + (size_t)rel * bc_str;
    const float* xpw = dir == 0 ? xpw0 : (dir == 1 ? xpw1 : xpw2);
    const float* dtw = dir == 0 ? dtw0 : (dir == 1 ? dtw1 : dtw2);
    const float* dtb = dir == 0 ? dtb0 : (dir == 1 ? dtb1 : dtb2);

    __shared__ float xrow[16][D_INNER];      // 32 KB
    __shared__ float xdbl[16][48];

    const size_t base = ((size_t)b * L_SEQ + p0) * D_INNER;
#pragma unroll
    for (int rep = 0; rep < 8; ++rep) {
        const int idx = rep * 256 + t;
        const int r = idx >> 7, c = (idx & 127) << 2;
        *(float4*)&xrow[r][c] = *(const float4*)(xc + base + (size_t)r * D_INNER + c);
    }
    __syncthreads();

    {
        const int j  = t & 63;
        const int rg = (t >> 6) << 2;
        if (j < 48) {
            float a0 = 0.f, a1 = 0.f, a2 = 0.f, a3 = 0.f;
            for (int c = 0; c < D_INNER; c += 4) {
                const float4 wv = *(const float4*)&xpw[(size_t)j * D_INNER + c];
                const float4 x0 = *(const float4*)&xrow[rg + 0][c];
                const float4 x1 = *(const float4*)&xrow[rg + 1][c];
                const float4 x2 = *(const float4*)&xrow[rg + 2][c];
                const float4 x3 = *(const float4*)&xrow[rg + 3][c];
                a0 = fmaf(wv.x, x0.x, fmaf(wv.y, x0.y, fmaf(wv.z, x0.z, fmaf(wv.w, x0.w, a0))));
                a1 = fmaf(wv.x, x1.x, fmaf(wv.y, x1.y, fmaf(wv.z, x1.z, fmaf(wv.w, x1.w, a1))));
                a2 = fmaf(wv.x, x2.x, fmaf(wv.y, x2.y, fmaf(wv.z, x2.z, fmaf(wv.w, x2.w, a2))));
                a3 = fmaf(wv.x, x3.x, fmaf(wv.y, x3.y, fmaf(wv.z, x3.z, fmaf(wv.w, x3.w, a3))));
            }
            xdbl[rg + 0][j] = a0; xdbl[rg + 1][j] = a1;
            xdbl[rg + 2][j] = a2; xdbl[rg + 3][j] = a3;
        }
    }
    __syncthreads();

#pragma unroll
    for (int jj = 0; jj < 2; ++jj) {
        const int dd = t + (jj << 8);
        const float4 w0 = *(const float4*)&dtw[dd * DT_RANK + 0];
        const float4 w1 = *(const float4*)&dtw[dd * DT_RANK + 4];
        const float4 w2 = *(const float4*)&dtw[dd * DT_RANK + 8];
        const float4 w3 = *(const float4*)&dtw[dd * DT_RANK + 12];
        const float bias = dtb[dd];
#pragma unroll 4
        for (int r = 0; r < 16; ++r) {
            float a = bias;
            a = fmaf(w0.x, xdbl[r][0],  fmaf(w0.y, xdbl[r][1],  fmaf(w0.z, xdbl[r][2],  fmaf(w0.w, xdbl[r][3],  a))));
            a = fmaf(w1.x, xdbl[r][4],  fmaf(w1.y, xdbl[r][5],  fmaf(w1.z, xdbl[r][6],  fmaf(w1.w, xdbl[r][7],  a))));
            a = fmaf(w2.x, xdbl[r][8],  fmaf(w2.y, xdbl[r][9],  fmaf(w2.z, xdbl[r][10], fmaf(w2.w, xdbl[r][11], a))));
            a = fmaf(w3.x, xdbl[r][12], fmaf(w3.y, xdbl[r][13], fmaf(w3.z, xdbl[r][14], fmaf(w3.w, xdbl[r][15], a))));
            dt[((size_t)b * L_SEQ + p0 + r) * D_INNER + dd] = softplus_f(a);
        }
    }
#pragma unroll
    for (int rep = 0; rep < 2; ++rep) {
        const int idx = rep * 256 + t;
        const int r = idx >> 5, c = idx & 31;
        bc[((size_t)b * L_SEQ + p0 + r) * 32 + c] = xdbl[r][16 + c];
    }
}

// ---------------------------------------------------------------------------
// Kernel 4a: per-chunk transition, channel-per-thread.
// ---------------------------------------------------------------------------
__global__ __launch_bounds__(256) void k_scan1(
    const float* __restrict__ dtY, const float* __restrict__ xcb,
    const float* __restrict__ bcb,
    const float* __restrict__ Al0, const float* __restrict__ Al1, const float* __restrict__ Al2,
    float* __restrict__ Pbb, float* __restrict__ Fbb,
    int dir_base, size_t big_str, size_t bc_str, size_t pf_str)
{
    const int rel = blockIdx.x >> 8;         // 256 blocks per dir
    const int rem = blockIdx.x & 255;
    const int dir = dir_base + rel;
    const int b     = rem >> 7;
    const int chunk = (rem >> 1) & 63;
    const int half  = rem & 1;
    const int t = threadIdx.x;
    const int d = half * 256 + t;

    const float* dt = dtY + (size_t)dir * SZ_BIGC;
    const float* xc = xcb + (size_t)rel * big_str;
    const float* bc = bcb + (size_t)rel * bc_str;
    const float* Al = dir == 0 ? Al0 : (dir == 1 ? Al1 : Al2);
    float* Pb = Pbb + (size_t)rel * pf_str;
    float* Fb = Fbb + (size_t)rel * pf_str;

    float As2[16];
    {
        const float* ap = Al + d * D_STATE;
#pragma unroll
        for (int s4 = 0; s4 < 4; ++s4) {
            const float4 a = *(const float4*)(ap + s4 * 4);
            As2[s4 * 4 + 0] = -__expf(a.x) * 1.44269504f;
            As2[s4 * 4 + 1] = -__expf(a.y) * 1.44269504f;
            As2[s4 * 4 + 2] = -__expf(a.z) * 1.44269504f;
            As2[s4 * 4 + 3] = -__expf(a.w) * 1.44269504f;
        }
    }
    float h[16];
#pragma unroll
    for (int s = 0; s < 16; ++s) h[s] = 0.f;
    float sumdt = 0.f;

    __shared__ float dts[16][256];   // 16 KB
    __shared__ float xcs[16][256];   // 16 KB
    __shared__ float bcs[16][16];    // 1 KB

    const size_t rowbase = (size_t)b * L_SEQ + chunk * CHUNK;
    const float* dtp = dt + rowbase * D_INNER + half * 256;
    const float* xcp = xc + rowbase * D_INNER + half * 256;
    const float* bcp = bc + rowbase * 32;

    for (int tile = 0; tile < 4; ++tile) {
        const int p0 = tile * 16;
#pragma unroll
        for (int rep = 0; rep < 4; ++rep) {
            const int idx = rep * 256 + t;           // 1024 float4
            const int jr = idx >> 6, c4 = (idx & 63) << 2;
            *(float4*)&dts[jr][c4] = *(const float4*)(dtp + (size_t)(p0 + jr) * D_INNER + c4);
            *(float4*)&xcs[jr][c4] = *(const float4*)(xcp + (size_t)(p0 + jr) * D_INNER + c4);
        }
        if (t < 64) {
            const int jr = t >> 2, c4 = (t & 3) << 2;
            *(float4*)&bcs[jr][c4] = *(const float4*)(bcp + (size_t)(p0 + jr) * 32 + c4);
        }
        __syncthreads();

#pragma unroll
        for (int j = 0; j < 16; ++j) {
            const float dtv = dts[j][t];
            const float xv  = xcs[j][t];
            sumdt += dtv;
            const float dtx = dtv * xv;
            float Bv[16];
#pragma unroll
            for (int s4 = 0; s4 < 4; ++s4) {
                const float4 bb = *(const float4*)&bcs[j][s4 * 4];
                Bv[s4 * 4 + 0] = bb.x; Bv[s4 * 4 + 1] = bb.y;
                Bv[s4 * 4 + 2] = bb.z; Bv[s4 * 4 + 3] = bb.w;
            }
#pragma unroll
            for (int s = 0; s < 16; ++s)
                h[s] = fmaf(exp2f(dtv * As2[s]), h[s], dtx * Bv[s]);
        }
        __syncthreads();
    }
    const size_t o = (((size_t)b * NCHUNK + chunk) * D_INNER + d) * D_STATE;
#pragma unroll
    for (int s = 0; s < 16; ++s) {
        Pb[o + s] = exp2f(As2[s] * sumdt);
        Fb[o + s] = h[s];
    }
}

// ---------------------------------------------------------------------------
// Kernel 4b: sequential combine over 64 chunks.
// ---------------------------------------------------------------------------
__global__ __launch_bounds__(256) void k_comb(
    const float* __restrict__ Pbb, const float* __restrict__ Fbb,
    float* __restrict__ Hinb, size_t pf_str)
{
    const int rel = blockIdx.x >> 6;         // 64 blocks per dir
    const int gid = (blockIdx.x & 63) * 256 + threadIdx.x;   // 16384
    const int b   = gid >> 13;
    const int rem = gid & 8191;
    const float* Pb = Pbb + (size_t)rel * pf_str;
    const float* Fb = Fbb + (size_t)rel * pf_str;
    float* Hin      = Hinb + (size_t)rel * pf_str;
    float h = 0.f;
    for (int c = 0; c < NCHUNK; ++c) {
        const size_t i = ((size_t)(b * NCHUNK + c) << 13) + rem;
        Hin[i] = h;
        h = Fb[i] + Pb[i] * h;
    }
}

// ---------------------------------------------------------------------------
// Kernel 4c: full scan, channel-per-thread; y written in place over dt.
// ---------------------------------------------------------------------------
__global__ __launch_bounds__(256) void k_scan2(
    float* dty,                               // dt in, y out (same buffer!)
    const float* __restrict__ xcb, const float* __restrict__ bcb,
    const float* __restrict__ Al0, const float* __restrict__ Al1, const float* __restrict__ Al2,
    const float* __restrict__ Dp0, const float* __restrict__ Dp1, const float* __restrict__ Dp2,
    const float* __restrict__ Hinb,
    int dir_base, size_t big_str, size_t bc_str, size_t pf_str)
{
    const int rel = blockIdx.x >> 8;
    const int rem = blockIdx.x & 255;
    const int dir = dir_base + rel;
    const int b     = rem >> 7;
    const int chunk = (rem >> 1) & 63;
    const int half  = rem & 1;
    const int t = threadIdx.x;
    const int d = half * 256 + t;

    float* dt       = dty + (size_t)dir * SZ_BIGC;
    const float* xc = xcb + (size_t)rel * big_str;
    const float* bc = bcb + (size_t)rel * bc_str;
    const float* Al  = dir == 0 ? Al0 : (dir == 1 ? Al1 : Al2);
    const float* Dpp = dir == 0 ? Dp0 : (dir == 1 ? Dp1 : Dp2);
    const float* Hin = Hinb + (size_t)rel * pf_str;

    float As2[16];
    {
        const float* ap = Al + d * D_STATE;
#pragma unroll
        for (int s4 = 0; s4 < 4; ++s4) {
            const float4 a = *(const float4*)(ap + s4 * 4);
            As2[s4 * 4 + 0] = -__expf(a.x) * 1.44269504f;
            As2[s4 * 4 + 1] = -__expf(a.y) * 1.44269504f;
            As2[s4 * 4 + 2] = -__expf(a.z) * 1.44269504f;
            As2[s4 * 4 + 3] = -__expf(a.w) * 1.44269504f;
        }
    }
    const float Dv = Dpp[d];
    float h[16];
    {
        const size_t o = (((size_t)b * NCHUNK + chunk) * D_INNER + d) * D_STATE;
#pragma unroll
        for (int s4 = 0; s4 < 4; ++s4) {
            const float4 hv = *(const float4*)(Hin + o + s4 * 4);
            h[s4 * 4 + 0] = hv.x; h[s4 * 4 + 1] = hv.y;
            h[s4 * 4 + 2] = hv.z; h[s4 * 4 + 3] = hv.w;
        }
    }

    __shared__ float dts[16][256];
    __shared__ float xcs[16][256];
    __shared__ float bcs[16][32];    // B and C

    const size_t rowbase = (size_t)b * L_SEQ + chunk * CHUNK;
    float* dtp       = dt + rowbase * D_INNER + half * 256;
    const float* xcp = xc + rowbase * D_INNER + half * 256;
    const float* bcp = bc + rowbase * 32;

    for (int tile = 0; tile < 4; ++tile) {
        const int p0 = tile * 16;
#pragma unroll
        for (int rep = 0; rep < 4; ++rep) {
            const int idx = rep * 256 + t;
            const int jr = idx >> 6, c4 = (idx & 63) << 2;
            *(float4*)&dts[jr][c4] = *(const float4*)(dtp + (size_t)(p0 + jr) * D_INNER + c4);
            *(float4*)&xcs[jr][c4] = *(const float4*)(xcp + (size_t)(p0 + jr) * D_INNER + c4);
        }
        if (t < 128) {
            const int jr = t >> 3, c4 = (t & 7) << 2;
            *(float4*)&bcs[jr][c4] = *(const float4*)(bcp + (size_t)(p0 + jr) * 32 + c4);
        }
        __syncthreads();

#pragma unroll
        for (int j = 0; j < 16; ++j) {
            const float dtv = dts[j][t];
            const float xv  = xcs[j][t];
            const float dtx = dtv * xv;
            float Bv[16], Cv[16];
#pragma unroll
            for (int s4 = 0; s4 < 4; ++s4) {
                const float4 bb = *(const float4*)&bcs[j][s4 * 4];
                const float4 cc = *(const float4*)&bcs[j][16 + s4 * 4];
                Bv[s4 * 4 + 0] = bb.x; Bv[s4 * 4 + 1] = bb.y;
                Bv[s4 * 4 + 2] = bb.z; Bv[s4 * 4 + 3] = bb.w;
                Cv[s4 * 4 + 0] = cc.x; Cv[s4 * 4 + 1] = cc.y;
                Cv[s4 * 4 + 2] = cc.z; Cv[s4 * 4 + 3] = cc.w;
            }
            float y = xv * Dv;
#pragma unroll
            for (int s = 0; s < 16; ++s) {
                h[s] = fmaf(exp2f(dtv * As2[s]), h[s], dtx * Bv[s]);
                y = fmaf(h[s], Cv[s], y);
            }
            dtp[(size_t)(p0 + j) * D_INNER + t] = y;   // overwrite consumed dt
        }
        __syncthreads();
    }
}

// ---------------------------------------------------------------------------
// Kernel 5: out_proj via MFMA. A = W_out bf16 [256 j][512 K] (L2-resident),
// B = yt = (y0+y1[rev]+y2[T])*sz staged as bf16 in LDS (16B-slot XOR swizzle).
// D[j][l] written directly in transposed out layout + residual.
// Grid = 256 tiles of 32 l-rows.
// ---------------------------------------------------------------------------
__global__ __launch_bounds__(256) void k_out3_mfma(
    const float* __restrict__ yall, const float* __restrict__ sz,
    const short* __restrict__ Wob, const float* __restrict__ x,
    float* __restrict__ out)
{
    __shared__ short ytb[32][512];           // 32 KB
    const int tile = blockIdx.x;
    const int b  = tile >> 7;
    const int l0 = (tile & 127) << 5;
    const int t  = threadIdx.x;

    const float* y0 = yall;
    const float* y1 = yall + SZ_BIGC;
    const float* y2 = yall + 2 * SZ_BIGC;
    const size_t rb = (size_t)b * L_SEQ;

    // stage 32 rows x 64 chunks (8 floats each) -> bf16, swizzled 16B slots
#pragma unroll
    for (int it = 0; it < 8; ++it) {
        const int idx = it * 256 + t;        // 2048 chunks
        const int r  = idx >> 6;
        const int c8 = idx & 63;
        const int lrow = l0 + r;
        const int p1 = (L_SEQ - 1) - lrow;
        const int p2 = ((lrow & 63) << 6) | (lrow >> 6);
        const float* s0 = y0 + (rb + lrow) * D_INNER + c8 * 8;
        const float* s1 = y1 + (rb + p1)   * D_INNER + c8 * 8;
        const float* s2 = y2 + (rb + p2)   * D_INNER + c8 * 8;
        const float* ss = sz + (rb + lrow) * D_INNER + c8 * 8;
        short8v pk;
#pragma unroll
        for (int i = 0; i < 8; ++i)
            pk[i] = f2bf((s0[i] + s1[i] + s2[i]) * ss[i]);
        *(short8v*)&ytb[r][(c8 ^ (r & 7)) * 8] = pk;
    }
    __syncthreads();

    const int w = t >> 6, l = t & 63;
    const int lrow = l & 15, lk = l >> 4;
    const int nf = w & 1;                    // which 16-l block
    const int j0 = (w >> 1) * 128;           // 8 j-frags of 16
    const int brow = nf * 16 + lrow;

    f32x4 acc[8];
#pragma unroll
    for (int jf = 0; jf < 8; ++jf) acc[jf] = {0.f, 0.f, 0.f, 0.f};

#pragma unroll 4
    for (int kk = 0; kk < 16; ++kk) {
        const int c8 = kk * 4 + lk;
        const short8v bfrag = *(const short8v*)&ytb[brow][(c8 ^ (brow & 7)) * 8];
#pragma unroll
        for (int jf = 0; jf < 8; ++jf) {
            const short8v afrag = *(const short8v*)(
                Wob + (size_t)(j0 + jf * 16 + lrow) * D_INNER + kk * 32 + lk * 8);
            acc[jf] = __builtin_amdgcn_mfma_f32_16x16x32_bf16(afrag, bfrag, acc[jf], 0, 0, 0);
        }
    }

    const int lcol = l0 + nf * 16 + lrow;
#pragma unroll
    for (int jf = 0; jf < 8; ++jf) {
        const int jr0 = j0 + jf * 16 + lk * 4;
#pragma unroll
        for (int j = 0; j < 4; ++j) {
            const size_t o = ((size_t)b * DIM + jr0 + j) * L_SEQ + lcol;
            out[o] = x[o] + acc[jf][j];
        }
    }
}

// ---------------------------------------------------------------------------
extern "C" void kernel_launch(void* const* d_in, const int* in_sizes, int n_in,
                              void* d_out, int out_size, void* d_ws, size_t ws_size,
                              hipStream_t stream)
{
    const float* x       = (const float*)d_in[0];
    const float* ln_w    = (const float*)d_in[1];
    const float* ln_b    = (const float*)d_in[2];
    const float* in_proj = (const float*)d_in[3];
    const float* conv_w[3] = {(const float*)d_in[4],  (const float*)d_in[10], (const float*)d_in[16]};
    const float* conv_b[3] = {(const float*)d_in[5],  (const float*)d_in[11], (const float*)d_in[17]};
    const float* xpw[3]    = {(const float*)d_in[6],  (const float*)d_in[12], (const float*)d_in[18]};
    const float* dtw[3]    = {(const float*)d_in[7],  (const float*)d_in[13], (const float*)d_in[19]};
    const float* dtb[3]    = {(const float*)d_in[8],  (const float*)d_in[14], (const float*)d_in[20]};
    const float* Dp[3]     = {(const float*)d_in[9],  (const float*)d_in[15], (const float*)d_in[21]};
    const float* A_log[3]  = {(const float*)d_in[22], (const float*)d_in[23], (const float*)d_in[24]};
    const float* out_proj  = (const float*)d_in[25];
    float* out = (float*)d_out;
    (void)in_sizes; (void)n_in; (void)out_size;

    const size_t NROW   = (size_t)B_SZ * L_SEQ;                       // 8192
    const size_t SZ_XNB = NROW * DIM / 2;                             // bf16 as float slots
    const size_t SZ_WIB = 1024 * 256 / 2;
    const size_t SZ_WOB = 256 * 512 / 2;
    const size_t SZ_BIG = NROW * D_INNER;                             // 4M
    const size_t SZ_BC  = NROW * 32;                                  // 256K
    const size_t SZ_PF  = (size_t)B_SZ * NCHUNK * D_INNER * D_STATE;  // 1M

    const size_t need_merged =
        SZ_XNB + SZ_WIB + SZ_WOB + 2 * SZ_BIG + 3 * SZ_BIG +
        3 * SZ_BIG + 3 * SZ_BC + 9 * SZ_PF;
    const bool merged = ws_size >= need_merged * sizeof(float);
    const int ndir = merged ? 3 : 1;
    const size_t big_str = merged ? SZ_BIG : 0;
    const size_t bc_str  = merged ? SZ_BC  : 0;
    const size_t pf_str  = merged ? SZ_PF  : 0;

    float* ws   = (float*)d_ws;
    short* xnb  = (short*)ws;
    short* Wib  = (short*)(ws + SZ_XNB);
    short* Wob  = (short*)(ws + SZ_XNB + SZ_WIB);
    float* xin  = ws + SZ_XNB + SZ_WIB + SZ_WOB;
    float* sz   = xin + SZ_BIG;
    float* dtY  = sz  + SZ_BIG;             // ALWAYS 3 buffers; y aliases dt
    float* p    = dtY + 3 * SZ_BIG;
    float* xc   = p;  p += (size_t)ndir * SZ_BIG;
    float* bc   = p;  p += (size_t)ndir * SZ_BC;
    float* Pb   = p;  p += (size_t)ndir * SZ_PF;
    float* Fb   = p;  p += (size_t)ndir * SZ_PF;
    float* Hin  = p;  p += (size_t)ndir * SZ_PF;

    k_cvt<<<dim3(384), dim3(256), 0, stream>>>(in_proj, out_proj, Wib, Wob);
    k_ln_t<<<dim3(B_SZ * 64), dim3(256), 0, stream>>>(x, ln_w, ln_b, xnb);
    k_inproj_mfma<<<dim3(512), dim3(256), 0, stream>>>(xnb, Wib, xin, sz);

    for (int d0 = 0; d0 < 3; d0 += ndir) {
        k_conv3<<<dim3(512 * ndir), dim3(256), 0, stream>>>(
            xin, conv_w[0], conv_w[1], conv_w[2],
            conv_b[0], conv_b[1], conv_b[2], xc, d0, big_str);
        k_proj3<<<dim3(512 * ndir), dim3(256), 0, stream>>>(
            xc, xpw[0], xpw[1], xpw[2], dtw[0], dtw[1], dtw[2],
            dtb[0], dtb[1], dtb[2], dtY, bc, d0, big_str, bc_str);
        k_scan1<<<dim3(256 * ndir), dim3(256), 0, stream>>>(
            dtY, xc, bc, A_log[0], A_log[1], A_log[2], Pb, Fb,
            d0, big_str, bc_str, pf_str);
        k_comb<<<dim3(64 * ndir), dim3(256), 0, stream>>>(Pb, Fb, Hin, pf_str);
        k_scan2<<<dim3(256 * ndir), dim3(256), 0, stream>>>(
            dtY, xc, bc, A_log[0], A_log[1], A_log[2],
            Dp[0], Dp[1], Dp[2], Hin, d0, big_str, bc_str, pf_str);
    }

    k_out3_mfma<<<dim3(256), dim3(256), 0, stream>>>(
        dtY, sz, Wob, x, out);
}

// Round 6
// 314.601 us; speedup vs baseline: 12.0161x; 1.1958x over previous
//
#include <hip/hip_runtime.h>
#include <hip/hip_bf16.h>
#include <cstdint>

#define B_SZ 2
#define DIM 256
#define L_SEQ 4096
#define D_INNER 512
#define DT_RANK 16
#define D_STATE 16
#define NCHUNK 64
#define CHUNK 64

static constexpr size_t SZ_BIG_SH = (size_t)B_SZ * L_SEQ * D_INNER;  // 4M elems

typedef __attribute__((ext_vector_type(8))) short short8v;
typedef __attribute__((ext_vector_type(4))) short short4v;
typedef __attribute__((ext_vector_type(4))) float f32x4;

__device__ __forceinline__ float silu_f(float v) {
    return v / (1.0f + __expf(-v));
}
__device__ __forceinline__ float softplus_f(float v) {
    return (v > 20.0f) ? v : log1pf(__expf(v));
}
__device__ __forceinline__ short f2bf(float f) {   // RNE fp32 -> bf16 bits
    uint32_t u = __float_as_uint(f);
    u += 0x7fffu + ((u >> 16) & 1u);
    return (short)(u >> 16);
}
__device__ __forceinline__ float bf2f(short s) {
    return __uint_as_float(((uint32_t)(uint16_t)s) << 16);
}
// direction map: sequence position p -> original flat index l (involutions)
__device__ __forceinline__ int dir_map(int p, int dm) {
    if (dm == 0) return p;
    if (dm == 1) return (L_SEQ - 1) - p;
    return ((p & 63) << 6) | (p >> 6);   // 64x64 transpose
}

// ---------------------------------------------------------------------------
// Kernel 0: convert weights to bf16: in_proj [1024][256], out_proj [256][512],
// x_proj[3] [48][512], dt_proj[3] [512][16].
// ---------------------------------------------------------------------------
__global__ __launch_bounds__(256) void k_cvt(
    const float* __restrict__ Wi, const float* __restrict__ Wo,
    const float* __restrict__ xp0, const float* __restrict__ xp1, const float* __restrict__ xp2,
    const float* __restrict__ dw0, const float* __restrict__ dw1, const float* __restrict__ dw2,
    short* __restrict__ Wib, short* __restrict__ Wob,
    short* __restrict__ xpwb, short* __restrict__ dtwb)
{
    const int idx = blockIdx.x * 256 + threadIdx.x;   // float4 chunk id
    const float* src; short* dst; int off;
    if (idx < 65536)        { src = Wi; dst = Wib; off = idx; }
    else if (idx < 98304)   { src = Wo; dst = Wob; off = idx - 65536; }
    else if (idx < 116736)  {
        int k = idx - 98304; const int d = k / 6144; k -= d * 6144;
        src = d == 0 ? xp0 : (d == 1 ? xp1 : xp2);
        dst = xpwb + (size_t)d * 24576; off = k;
    } else {
        int k = idx - 116736; const int d = k / 2048; k -= d * 2048;
        src = d == 0 ? dw0 : (d == 1 ? dw1 : dw2);
        dst = dtwb + (size_t)d * 8192; off = k;
    }
    const float4 v = *(const float4*)(src + (size_t)off * 4);
    short4v p = {f2bf(v.x), f2bf(v.y), f2bf(v.z), f2bf(v.w)};
    *(short4v*)(dst + (size_t)off * 4) = p;
}

// ---------------------------------------------------------------------------
// Kernel 1a: LayerNorm via LDS transpose tile; writes xn as bf16.
// ---------------------------------------------------------------------------
__global__ __launch_bounds__(256) void k_ln_t(
    const float* __restrict__ x, const float* __restrict__ lnw,
    const float* __restrict__ lnb, short* __restrict__ xnb)
{
    __shared__ float xt[64][257];
    __shared__ float red[2][4][64];
    __shared__ float muS[64], rsS[64];
    __shared__ float lnwS[DIM], lnbS[DIM];

    const int b  = blockIdx.x >> 6;
    const int l0 = (blockIdx.x & 63) << 6;
    const int t  = threadIdx.x;
    lnwS[t] = lnw[t]; lnbS[t] = lnb[t];

    const float* xb = x + (size_t)b * DIM * L_SEQ + l0;
#pragma unroll
    for (int it = 0; it < 16; ++it) {
        const int idx = it * 256 + t;
        const int c = idx >> 4, pos = (idx & 15) << 2;
        const float4 v = *(const float4*)(xb + (size_t)c * L_SEQ + pos);
        xt[pos + 0][c] = v.x; xt[pos + 1][c] = v.y;
        xt[pos + 2][c] = v.z; xt[pos + 3][c] = v.w;
    }
    __syncthreads();
    {
        const int l = t & 63, cq = t >> 6;
        float sum = 0.f, sq = 0.f;
        for (int c = cq * 64; c < cq * 64 + 64; ++c) {
            const float v = xt[l][c];
            sum += v; sq += v * v;
        }
        red[0][cq][l] = sum; red[1][cq][l] = sq;
    }
    __syncthreads();
    if (t < 64) {
        const float s  = red[0][0][t] + red[0][1][t] + red[0][2][t] + red[0][3][t];
        const float q2 = red[1][0][t] + red[1][1][t] + red[1][2][t] + red[1][3][t];
        const float mu  = s * (1.0f / DIM);
        const float var = q2 * (1.0f / DIM) - mu * mu;
        muS[t] = mu; rsS[t] = rsqrtf(var + 1e-5f);
    }
    __syncthreads();
#pragma unroll
    for (int it = 0; it < 32; ++it) {
        const int idx = it * 256 + t;
        const int l = idx >> 7, cp = (idx & 127) << 1;
        const float mu = muS[l], rs = rsS[l];
        short2 p;
        p.x = f2bf((xt[l][cp + 0] - mu) * rs * lnwS[cp + 0] + lnbS[cp + 0]);
        p.y = f2bf((xt[l][cp + 1] - mu) * rs * lnwS[cp + 1] + lnbS[cp + 1]);
        *(short2*)(xnb + (size_t)((b * L_SEQ) + l0 + l) * DIM + cp) = p;
    }
}

// ---------------------------------------------------------------------------
// Kernel 1b: in_proj via MFMA; outputs xin and sz as bf16.
// ---------------------------------------------------------------------------
__global__ __launch_bounds__(256) void k_inproj_mfma(
    const short* __restrict__ xnb, const short* __restrict__ Wib,
    short* __restrict__ xinb, short* __restrict__ szb)
{
    const int mblk = blockIdx.x >> 2;
    const int q    = blockIdx.x & 3;
    const int t = threadIdx.x;
    const int w = t >> 6, l = t & 63;
    const int m0 = mblk * 64 + w * 16;
    const int n0 = q * 256;
    const int lrow = l & 15, lk = l >> 4;

    short8v a[8];
    {
        const short* ap = xnb + (size_t)(m0 + lrow) * DIM + lk * 8;
#pragma unroll
        for (int kk = 0; kk < 8; ++kk)
            a[kk] = *(const short8v*)(ap + kk * 32);
    }

#pragma unroll 4
    for (int nf = 0; nf < 16; ++nf) {
        const int n = n0 + nf * 16 + lrow;
        const short* bp = Wib + (size_t)n * DIM + lk * 8;
        f32x4 acc = {0.f, 0.f, 0.f, 0.f};
#pragma unroll
        for (int kk = 0; kk < 8; ++kk)
            acc = __builtin_amdgcn_mfma_f32_16x16x32_bf16(
                a[kk], *(const short8v*)(bp + kk * 32), acc, 0, 0, 0);
        const int col = n;
        const int r0  = m0 + lk * 4;
        if (n0 < D_INNER) {
#pragma unroll
            for (int j = 0; j < 4; ++j)
                xinb[(size_t)(r0 + j) * D_INNER + col] = f2bf(acc[j]);
        } else {
#pragma unroll
            for (int j = 0; j < 4; ++j)
                szb[(size_t)(r0 + j) * D_INNER + (col - D_INNER)] = f2bf(silu_f(acc[j]));
        }
    }
}

// ---------------------------------------------------------------------------
// Kernel 2: causal conv (K=4) + SiLU; bf16 in (xinb), bf16 out (xcb).
// Sliding-window regs, 1 LDS read per output step.
// ---------------------------------------------------------------------------
__global__ __launch_bounds__(256) void k_conv3(
    const short* __restrict__ xinb,
    const float* __restrict__ cw0, const float* __restrict__ cw1, const float* __restrict__ cw2,
    const float* __restrict__ cb0, const float* __restrict__ cb1, const float* __restrict__ cb2,
    short* __restrict__ xcbb, int dir_base, size_t xcb_str)
{
    const int rel = blockIdx.x >> 9;
    const int rem = blockIdx.x & 511;
    const int dir = dir_base + rel;
    const int b   = rem >> 8;
    const int p0  = (rem & 255) << 4;
    const int t   = threadIdx.x;

    const float* cw = dir == 0 ? cw0 : (dir == 1 ? cw1 : cw2);
    const float* cb = dir == 0 ? cb0 : (dir == 1 ? cb1 : cb2);
    short* xcb = xcbb + (size_t)rel * xcb_str;

    __shared__ short s[19][D_INNER];   // 19.5 KB
    for (int i = 0; i < 19; ++i) {
        const int pk = p0 - 3 + i;
        short2 v = {0, 0};
        if (pk >= 0) {
            const int lo = dir_map(pk, dir);
            v = *(const short2*)(xinb + ((size_t)b * L_SEQ + lo) * D_INNER + t * 2);
        }
        *(short2*)&s[i][t * 2] = v;
    }
    __syncthreads();

#pragma unroll
    for (int half = 0; half < 2; ++half) {
        const int d = half * 256 + t;
        const float4 wv = *(const float4*)(cw + d * 4);
        const float bb = cb[d];
        float x0 = bf2f(s[0][d]), x1 = bf2f(s[1][d]), x2 = bf2f(s[2][d]);
#pragma unroll
        for (int i = 0; i < 16; ++i) {
            const float x3 = bf2f(s[i + 3][d]);
            const float a = bb + wv.x * x0 + wv.y * x1 + wv.z * x2 + wv.w * x3;
            xcb[((size_t)b * L_SEQ + p0 + i) * D_INNER + d] = f2bf(silu_f(a));
            x0 = x1; x1 = x2; x2 = x3;
        }
    }
}

// ---------------------------------------------------------------------------
// Kernel 3: x_proj + dt_proj, both via MFMA. Block = 64 rows (4 waves x 16).
// x_proj: A = xc bf16 rows, B = xpw bf16 [48][512]; nf0 -> dtr (LDS bf16),
// nf1/2 -> bc fp32 direct store. dt_proj: 16x16x32 MFMA with K=16 zero-pad;
// softplus epilogue; dt stored bf16.
// ---------------------------------------------------------------------------
__global__ __launch_bounds__(256) void k_proj3_mfma(
    const short* __restrict__ xcbb, const short* __restrict__ xpwb,
    const short* __restrict__ dtwb,
    const float* __restrict__ dtb0, const float* __restrict__ dtb1, const float* __restrict__ dtb2,
    short* __restrict__ dtYb, float* __restrict__ bcbuf,
    int dir_base, size_t xcb_str, size_t bc_str)
{
    const int rel = blockIdx.x >> 7;         // 128 blocks per dir
    const int rem = blockIdx.x & 127;
    const int dir = dir_base + rel;
    const int m0  = rem * 64;
    const int t = threadIdx.x;
    const int w = t >> 6, l = t & 63;
    const int lrow = l & 15, lk = l >> 4;

    const short* xcb = xcbb + (size_t)rel * xcb_str;
    const short* xpw = xpwb + (size_t)dir * (48 * 512);
    const short* dtw = dtwb + (size_t)dir * (512 * 16);
    const float* dtb = dir == 0 ? dtb0 : (dir == 1 ? dtb1 : dtb2);
    short* dt = dtYb + (size_t)dir * SZ_BIG_SH;
    float* bc = bcbuf + (size_t)rel * bc_str;

    __shared__ short xdblb[64][16];   // dtr bf16, 2 KB
    __shared__ float dtbS[512];

    dtbS[t] = dtb[t]; dtbS[t + 256] = dtb[t + 256];

    const int mw = m0 + w * 16;
    short8v a[16];
    {
        const short* ap = xcb + (size_t)(mw + lrow) * D_INNER + lk * 8;
#pragma unroll
        for (int kk = 0; kk < 16; ++kk)
            a[kk] = *(const short8v*)(ap + kk * 32);
    }

#pragma unroll
    for (int nf = 0; nf < 3; ++nf) {
        f32x4 acc = {0.f, 0.f, 0.f, 0.f};
        const short* bp = xpw + (size_t)(nf * 16 + lrow) * D_INNER + lk * 8;
#pragma unroll
        for (int kk = 0; kk < 16; ++kk)
            acc = __builtin_amdgcn_mfma_f32_16x16x32_bf16(
                a[kk], *(const short8v*)(bp + kk * 32), acc, 0, 0, 0);
        if (nf == 0) {
#pragma unroll
            for (int j = 0; j < 4; ++j)
                xdblb[w * 16 + lk * 4 + j][lrow] = f2bf(acc[j]);
        } else {
#pragma unroll
            for (int j = 0; j < 4; ++j)
                bc[(size_t)(mw + lk * 4 + j) * 32 + (nf - 1) * 16 + lrow] = acc[j];
        }
    }
    __syncthreads();

    // dt_proj MFMA (K=16 zero-padded to 32)
    short8v adt = {0, 0, 0, 0, 0, 0, 0, 0};
    if (lk < 2) adt = *(const short8v*)&xdblb[w * 16 + lrow][lk * 8];

#pragma unroll 4
    for (int nb = 0; nb < 32; ++nb) {
        short8v bdt = {0, 0, 0, 0, 0, 0, 0, 0};
        if (lk < 2) bdt = *(const short8v*)(dtw + (size_t)(nb * 16 + lrow) * 16 + lk * 8);
        f32x4 acc = {0.f, 0.f, 0.f, 0.f};
        acc = __builtin_amdgcn_mfma_f32_16x16x32_bf16(adt, bdt, acc, 0, 0, 0);
        const int d = nb * 16 + lrow;
        const float bias = dtbS[d];
#pragma unroll
        for (int j = 0; j < 4; ++j)
            dt[(size_t)(mw + lk * 4 + j) * D_INNER + d] = f2bf(softplus_f(acc[j] + bias));
    }
}

// ---------------------------------------------------------------------------
// Kernel 4a: per-chunk transition, channel-per-thread, bf16 dt/xc tiles.
// ---------------------------------------------------------------------------
__global__ __launch_bounds__(256) void k_scan1(
    const short* __restrict__ dtYb, const short* __restrict__ xcbb,
    const float* __restrict__ bcb,
    const float* __restrict__ Al0, const float* __restrict__ Al1, const float* __restrict__ Al2,
    float* __restrict__ Pbb, float* __restrict__ Fbb,
    int dir_base, size_t xcb_str, size_t bc_str, size_t pf_str)
{
    const int rel = blockIdx.x >> 8;
    const int rem = blockIdx.x & 255;
    const int dir = dir_base + rel;
    const int b     = rem >> 7;
    const int chunk = (rem >> 1) & 63;
    const int half  = rem & 1;
    const int t = threadIdx.x;
    const int d = half * 256 + t;

    const short* dtg = dtYb + (size_t)dir * SZ_BIG_SH;
    const short* xcg = xcbb + (size_t)rel * xcb_str;
    const float* bcg = bcb + (size_t)rel * bc_str;
    const float* Al = dir == 0 ? Al0 : (dir == 1 ? Al1 : Al2);
    float* Pb = Pbb + (size_t)rel * pf_str;
    float* Fb = Fbb + (size_t)rel * pf_str;

    float As2[16];
    {
        const float* ap = Al + d * D_STATE;
#pragma unroll
        for (int s4 = 0; s4 < 4; ++s4) {
            const float4 a = *(const float4*)(ap + s4 * 4);
            As2[s4 * 4 + 0] = -__expf(a.x) * 1.44269504f;
            As2[s4 * 4 + 1] = -__expf(a.y) * 1.44269504f;
            As2[s4 * 4 + 2] = -__expf(a.z) * 1.44269504f;
            As2[s4 * 4 + 3] = -__expf(a.w) * 1.44269504f;
        }
    }
    float h[16];
#pragma unroll
    for (int s = 0; s < 16; ++s) h[s] = 0.f;
    float sumdt = 0.f;

    __shared__ short dts[16][256];   // 8 KB
    __shared__ short xcs[16][256];   // 8 KB
    __shared__ float bcs[16][16];    // 1 KB

    const size_t rowbase = (size_t)b * L_SEQ + chunk * CHUNK;
    const short* dtp = dtg + rowbase * D_INNER + half * 256;
    const short* xcp = xcg + rowbase * D_INNER + half * 256;
    const float* bcp = bcg + rowbase * 32;

    for (int tile = 0; tile < 4; ++tile) {
        const int p0 = tile * 16;
#pragma unroll
        for (int rep = 0; rep < 2; ++rep) {
            const int idx = rep * 256 + t;           // 512 short8v
            const int jr = idx >> 5, c8 = (idx & 31) << 3;
            *(short8v*)&dts[jr][c8] = *(const short8v*)(dtp + (size_t)(p0 + jr) * D_INNER + c8);
            *(short8v*)&xcs[jr][c8] = *(const short8v*)(xcp + (size_t)(p0 + jr) * D_INNER + c8);
        }
        if (t < 64) {
            const int jr = t >> 2, c4 = (t & 3) << 2;
            *(float4*)&bcs[jr][c4] = *(const float4*)(bcp + (size_t)(p0 + jr) * 32 + c4);
        }
        __syncthreads();

#pragma unroll
        for (int j = 0; j < 16; ++j) {
            const float dtv = bf2f(dts[j][t]);
            const float xv  = bf2f(xcs[j][t]);
            sumdt += dtv;
            const float dtx = dtv * xv;
            float Bv[16];
#pragma unroll
            for (int s4 = 0; s4 < 4; ++s4) {
                const float4 bb = *(const float4*)&bcs[j][s4 * 4];
                Bv[s4 * 4 + 0] = bb.x; Bv[s4 * 4 + 1] = bb.y;
                Bv[s4 * 4 + 2] = bb.z; Bv[s4 * 4 + 3] = bb.w;
            }
#pragma unroll
            for (int s = 0; s < 16; ++s)
                h[s] = fmaf(exp2f(dtv * As2[s]), h[s], dtx * Bv[s]);
        }
        __syncthreads();
    }
    const size_t o = (((size_t)b * NCHUNK + chunk) * D_INNER + d) * D_STATE;
#pragma unroll
    for (int s = 0; s < 16; ++s) {
        Pb[o + s] = exp2f(As2[s] * sumdt);
        Fb[o + s] = h[s];
    }
}

// ---------------------------------------------------------------------------
// Kernel 4b: sequential combine over 64 chunks; Hin written IN PLACE over Pb.
// ---------------------------------------------------------------------------
__global__ __launch_bounds__(256) void k_comb(
    float* __restrict__ PbHin, const float* __restrict__ Fbb, size_t pf_str)
{
    const int rel = blockIdx.x >> 6;
    const int gid = (blockIdx.x & 63) * 256 + threadIdx.x;
    const int b   = gid >> 13;
    const int rem = gid & 8191;
    float* PH = PbHin + (size_t)rel * pf_str;
    const float* Fb = Fbb + (size_t)rel * pf_str;
    float h = 0.f;
    for (int c = 0; c < NCHUNK; ++c) {
        const size_t i = ((size_t)(b * NCHUNK + c) << 13) + rem;
        const float pv = PH[i];
        const float fv = Fb[i];
        PH[i] = h;
        h = fv + pv * h;
    }
}

// ---------------------------------------------------------------------------
// Kernel 4c: full scan; y = h.C + xc*D written bf16 IN PLACE over dt.
// ---------------------------------------------------------------------------
__global__ __launch_bounds__(256) void k_scan2(
    short* dtYb,                              // bf16 dt in, bf16 y out
    const short* __restrict__ xcbb, const float* __restrict__ bcb,
    const float* __restrict__ Al0, const float* __restrict__ Al1, const float* __restrict__ Al2,
    const float* __restrict__ Dp0, const float* __restrict__ Dp1, const float* __restrict__ Dp2,
    const float* __restrict__ Hinb,
    int dir_base, size_t xcb_str, size_t bc_str, size_t pf_str)
{
    const int rel = blockIdx.x >> 8;
    const int rem = blockIdx.x & 255;
    const int dir = dir_base + rel;
    const int b     = rem >> 7;
    const int chunk = (rem >> 1) & 63;
    const int half  = rem & 1;
    const int t = threadIdx.x;
    const int d = half * 256 + t;

    short* dtg      = dtYb + (size_t)dir * SZ_BIG_SH;
    const short* xcg = xcbb + (size_t)rel * xcb_str;
    const float* bcg = bcb + (size_t)rel * bc_str;
    const float* Al  = dir == 0 ? Al0 : (dir == 1 ? Al1 : Al2);
    const float* Dpp = dir == 0 ? Dp0 : (dir == 1 ? Dp1 : Dp2);
    const float* Hin = Hinb + (size_t)rel * pf_str;

    float As2[16];
    {
        const float* ap = Al + d * D_STATE;
#pragma unroll
        for (int s4 = 0; s4 < 4; ++s4) {
            const float4 a = *(const float4*)(ap + s4 * 4);
            As2[s4 * 4 + 0] = -__expf(a.x) * 1.44269504f;
            As2[s4 * 4 + 1] = -__expf(a.y) * 1.44269504f;
            As2[s4 * 4 + 2] = -__expf(a.z) * 1.44269504f;
            As2[s4 * 4 + 3] = -__expf(a.w) * 1.44269504f;
        }
    }
    const float Dv = Dpp[d];
    float h[16];
    {
        const size_t o = (((size_t)b * NCHUNK + chunk) * D_INNER + d) * D_STATE;
#pragma unroll
        for (int s4 = 0; s4 < 4; ++s4) {
            const float4 hv = *(const float4*)(Hin + o + s4 * 4);
            h[s4 * 4 + 0] = hv.x; h[s4 * 4 + 1] = hv.y;
            h[s4 * 4 + 2] = hv.z; h[s4 * 4 + 3] = hv.w;
        }
    }

    __shared__ short dts[16][256];
    __shared__ short xcs[16][256];
    __shared__ float bcs[16][32];

    const size_t rowbase = (size_t)b * L_SEQ + chunk * CHUNK;
    short* dtp       = dtg + rowbase * D_INNER + half * 256;
    const short* xcp = xcg + rowbase * D_INNER + half * 256;
    const float* bcp = bcg + rowbase * 32;

    for (int tile = 0; tile < 4; ++tile) {
        const int p0 = tile * 16;
#pragma unroll
        for (int rep = 0; rep < 2; ++rep) {
            const int idx = rep * 256 + t;
            const int jr = idx >> 5, c8 = (idx & 31) << 3;
            *(short8v*)&dts[jr][c8] = *(const short8v*)(dtp + (size_t)(p0 + jr) * D_INNER + c8);
            *(short8v*)&xcs[jr][c8] = *(const short8v*)(xcp + (size_t)(p0 + jr) * D_INNER + c8);
        }
        if (t < 128) {
            const int jr = t >> 3, c4 = (t & 7) << 2;
            *(float4*)&bcs[jr][c4] = *(const float4*)(bcp + (size_t)(p0 + jr) * 32 + c4);
        }
        __syncthreads();

#pragma unroll
        for (int j = 0; j < 16; ++j) {
            const float dtv = bf2f(dts[j][t]);
            const float xv  = bf2f(xcs[j][t]);
            const float dtx = dtv * xv;
            float Bv[16], Cv[16];
#pragma unroll
            for (int s4 = 0; s4 < 4; ++s4) {
                const float4 bb = *(const float4*)&bcs[j][s4 * 4];
                const float4 cc = *(const float4*)&bcs[j][16 + s4 * 4];
                Bv[s4 * 4 + 0] = bb.x; Bv[s4 * 4 + 1] = bb.y;
                Bv[s4 * 4 + 2] = bb.z; Bv[s4 * 4 + 3] = bb.w;
                Cv[s4 * 4 + 0] = cc.x; Cv[s4 * 4 + 1] = cc.y;
                Cv[s4 * 4 + 2] = cc.z; Cv[s4 * 4 + 3] = cc.w;
            }
            float y = xv * Dv;
#pragma unroll
            for (int s = 0; s < 16; ++s) {
                h[s] = fmaf(exp2f(dtv * As2[s]), h[s], dtx * Bv[s]);
                y = fmaf(h[s], Cv[s], y);
            }
            dtp[(size_t)(p0 + j) * D_INNER + t] = f2bf(y);
        }
        __syncthreads();
    }
}

// ---------------------------------------------------------------------------
// Kernel 5: out_proj via MFMA; y0/y1/y2/sz all bf16.
// ---------------------------------------------------------------------------
__global__ __launch_bounds__(256) void k_out3_mfma(
    const short* __restrict__ yall, const short* __restrict__ szb,
    const short* __restrict__ Wob, const float* __restrict__ x,
    float* __restrict__ out)
{
    __shared__ short ytb[32][512];           // 32 KB
    const int tile = blockIdx.x;
    const int b  = tile >> 7;
    const int l0 = (tile & 127) << 5;
    const int t  = threadIdx.x;

    const short* y0 = yall;
    const short* y1 = yall + SZ_BIG_SH;
    const short* y2 = yall + 2 * SZ_BIG_SH;
    const size_t rb = (size_t)b * L_SEQ;

#pragma unroll
    for (int it = 0; it < 8; ++it) {
        const int idx = it * 256 + t;        // 2048 chunks of 8
        const int r  = idx >> 6;
        const int c8 = idx & 63;
        const int lrow = l0 + r;
        const int p1 = (L_SEQ - 1) - lrow;
        const int p2 = ((lrow & 63) << 6) | (lrow >> 6);
        const short8v s0 = *(const short8v*)(y0 + (rb + lrow) * D_INNER + c8 * 8);
        const short8v s1 = *(const short8v*)(y1 + (rb + p1)   * D_INNER + c8 * 8);
        const short8v s2 = *(const short8v*)(y2 + (rb + p2)   * D_INNER + c8 * 8);
        const short8v sv = *(const short8v*)(szb + (rb + lrow) * D_INNER + c8 * 8);
        short8v pk;
#pragma unroll
        for (int i = 0; i < 8; ++i)
            pk[i] = f2bf((bf2f(s0[i]) + bf2f(s1[i]) + bf2f(s2[i])) * bf2f(sv[i]));
        *(short8v*)&ytb[r][(c8 ^ (r & 7)) * 8] = pk;
    }
    __syncthreads();

    const int w = t >> 6, l = t & 63;
    const int lrow = l & 15, lk = l >> 4;
    const int nf = w & 1;
    const int j0 = (w >> 1) * 128;
    const int brow = nf * 16 + lrow;

    f32x4 acc[8];
#pragma unroll
    for (int jf = 0; jf < 8; ++jf) acc[jf] = {0.f, 0.f, 0.f, 0.f};

#pragma unroll 4
    for (int kk = 0; kk < 16; ++kk) {
        const int c8 = kk * 4 + lk;
        const short8v bfrag = *(const short8v*)&ytb[brow][(c8 ^ (brow & 7)) * 8];
#pragma unroll
        for (int jf = 0; jf < 8; ++jf) {
            const short8v afrag = *(const short8v*)(
                Wob + (size_t)(j0 + jf * 16 + lrow) * D_INNER + kk * 32 + lk * 8);
            acc[jf] = __builtin_amdgcn_mfma_f32_16x16x32_bf16(afrag, bfrag, acc[jf], 0, 0, 0);
        }
    }

    const int lcol = l0 + nf * 16 + lrow;
#pragma unroll
    for (int jf = 0; jf < 8; ++jf) {
        const int jr0 = j0 + jf * 16 + lk * 4;
#pragma unroll
        for (int j = 0; j < 4; ++j) {
            const size_t o = ((size_t)b * DIM + jr0 + j) * L_SEQ + lcol;
            out[o] = x[o] + acc[jf][j];
        }
    }
}

// ---------------------------------------------------------------------------
extern "C" void kernel_launch(void* const* d_in, const int* in_sizes, int n_in,
                              void* d_out, int out_size, void* d_ws, size_t ws_size,
                              hipStream_t stream)
{
    const float* x       = (const float*)d_in[0];
    const float* ln_w    = (const float*)d_in[1];
    const float* ln_b    = (const float*)d_in[2];
    const float* in_proj = (const float*)d_in[3];
    const float* conv_w[3] = {(const float*)d_in[4],  (const float*)d_in[10], (const float*)d_in[16]};
    const float* conv_b[3] = {(const float*)d_in[5],  (const float*)d_in[11], (const float*)d_in[17]};
    const float* xpw[3]    = {(const float*)d_in[6],  (const float*)d_in[12], (const float*)d_in[18]};
    const float* dtw[3]    = {(const float*)d_in[7],  (const float*)d_in[13], (const float*)d_in[19]};
    const float* dtb[3]    = {(const float*)d_in[8],  (const float*)d_in[14], (const float*)d_in[20]};
    const float* Dp[3]     = {(const float*)d_in[9],  (const float*)d_in[15], (const float*)d_in[21]};
    const float* A_log[3]  = {(const float*)d_in[22], (const float*)d_in[23], (const float*)d_in[24]};
    const float* out_proj  = (const float*)d_in[25];
    float* out = (float*)d_out;
    (void)in_sizes; (void)n_in; (void)out_size;

    const size_t NROW   = (size_t)B_SZ * L_SEQ;                       // 8192
    // float-slot sizes
    const size_t SZ_XNB = NROW * DIM / 2;            // 1,048,576
    const size_t SZ_WIB = 262144 / 2;
    const size_t SZ_WOB = 131072 / 2;
    const size_t SZ_XPW = 3 * 24576 / 2;
    const size_t SZ_DTW = 3 * 8192 / 2;
    const size_t SZ_BH  = NROW * D_INNER / 2;        // bf16 big buf = 2,097,152
    const size_t SZ_BC  = NROW * 32;                 // 262,144
    const size_t SZ_PF  = (size_t)B_SZ * NCHUNK * D_INNER * D_STATE;  // 1,048,576

    const size_t need_merged =
        SZ_XNB + SZ_WIB + SZ_WOB + SZ_XPW + SZ_DTW +
        2 * SZ_BH + 3 * SZ_BH + 3 * SZ_BH + 3 * SZ_BC + 6 * SZ_PF;
    const bool merged = ws_size >= need_merged * sizeof(float);
    const int ndir = merged ? 3 : 1;
    const size_t xcb_str = merged ? (SZ_BH * 2) : 0;   // SHORT units
    const size_t bc_str  = merged ? SZ_BC : 0;
    const size_t pf_str  = merged ? SZ_PF : 0;

    float* ws   = (float*)d_ws;
    float* p    = ws;
    short* xnb  = (short*)p;  p += SZ_XNB;
    short* Wib  = (short*)p;  p += SZ_WIB;
    short* Wob  = (short*)p;  p += SZ_WOB;
    short* xpwb = (short*)p;  p += SZ_XPW;
    short* dtwb = (short*)p;  p += SZ_DTW;
    short* xinb = (short*)p;  p += SZ_BH;
    short* szb  = (short*)p;  p += SZ_BH;
    short* dtYb = (short*)p;  p += 3 * SZ_BH;          // y in-place, 3 dirs
    short* xcbb = (short*)p;  p += (size_t)ndir * SZ_BH;
    float* bc   = p;          p += (size_t)ndir * SZ_BC;
    float* Pb   = p;          p += (size_t)ndir * SZ_PF;   // Hin in-place
    float* Fb   = p;          p += (size_t)ndir * SZ_PF;

    k_cvt<<<dim3(480), dim3(256), 0, stream>>>(
        in_proj, out_proj, xpw[0], xpw[1], xpw[2], dtw[0], dtw[1], dtw[2],
        Wib, Wob, xpwb, dtwb);
    k_ln_t<<<dim3(B_SZ * 64), dim3(256), 0, stream>>>(x, ln_w, ln_b, xnb);
    k_inproj_mfma<<<dim3(512), dim3(256), 0, stream>>>(xnb, Wib, xinb, szb);

    for (int d0 = 0; d0 < 3; d0 += ndir) {
        k_conv3<<<dim3(512 * ndir), dim3(256), 0, stream>>>(
            xinb, conv_w[0], conv_w[1], conv_w[2],
            conv_b[0], conv_b[1], conv_b[2], xcbb, d0, xcb_str);
        k_proj3_mfma<<<dim3(128 * ndir), dim3(256), 0, stream>>>(
            xcbb, xpwb, dtwb, dtb[0], dtb[1], dtb[2],
            dtYb, bc, d0, xcb_str, bc_str);
        k_scan1<<<dim3(256 * ndir), dim3(256), 0, stream>>>(
            dtYb, xcbb, bc, A_log[0], A_log[1], A_log[2], Pb, Fb,
            d0, xcb_str, bc_str, pf_str);
        k_comb<<<dim3(64 * ndir), dim3(256), 0, stream>>>(Pb, Fb, pf_str);
        k_scan2<<<dim3(256 * ndir), dim3(256), 0, stream>>>(
            dtYb, xcbb, bc, A_log[0], A_log[1], A_log[2],
            Dp[0], Dp[1], Dp[2], Pb, d0, xcb_str, bc_str, pf_str);
    }

    k_out3_mfma<<<dim3(256), dim3(256), 0, stream>>>(
        dtYb, szb, Wob, x, out);
}